// Round 11
// baseline (278.482 us; speedup 1.0000x reference)
//
#include <hip/hip_runtime.h>
#include <math.h>

#define N_NODES 200000
#define E_EDGES 100000
#define TIME_DIM 100
#define RAW_DIM 484   // 128 + 128 + 128 + 100
#define OVF_MAX 8192
#define INVALID_NODE 0xFFFFFFFFu

typedef short  bf16x8 __attribute__((ext_vector_type(8)));
typedef float  f32x4  __attribute__((ext_vector_type(4)));
typedef unsigned int uint;

__device__ __forceinline__ short f2bf(float f) {
    unsigned u = __builtin_bit_cast(unsigned, f);
    u = (u + 0x7FFFu + ((u >> 16) & 1u)) >> 16;   // RNE
    return (short)u;
}
__device__ __forceinline__ float bf2f(unsigned short u) {
    return __builtin_bit_cast(float, ((unsigned)u) << 16);
}
__device__ __forceinline__ float fsigmoid(float x) {
    return __builtin_amdgcn_rcpf(1.0f + __expf(-x));
}
__device__ __forceinline__ float ftanh(float x) {
    float t = __expf(2.0f * x);
    return 1.0f - 2.0f * __builtin_amdgcn_rcpf(t + 1.0f);
}
__device__ __forceinline__ unsigned cvtpk(float a, float b) {
    unsigned r;
    asm("v_cvt_pk_bf16_f32 %0, %1, %2" : "=v"(r) : "v"(a), "v"(b));
    return r;
}
__device__ __forceinline__ bf16x8 pack8(float4 a, float4 b) {
    uint4 u = {cvtpk(a.x, a.y), cvtpk(a.z, a.w), cvtpk(b.x, b.y), cvtpk(b.z, b.w)};
    return __builtin_bit_cast(bf16x8, u);
}

// ---------------------------------------------------------------------------
// Setup: prep both weight fragments + ticket slot lists (+ active list).
//   blocks [0,512)    : pack W_big[512][256] (GRU) -> wfg
//   blocks [512,768)  : pack msg_W -> wfm (K padded to 512)
//   blocks [768,...)  : tickets (cnt/nact/ovf[0] pre-zeroed)
// ---------------------------------------------------------------------------
template<int CAPX, bool ACT>
__global__ __launch_bounds__(256) void tgn_setup(
    const float* __restrict__ Wih, const float* __restrict__ Whh,
    short* __restrict__ wfg,
    const float* __restrict__ msgW, short* __restrict__ wfm,
    const int* __restrict__ src, const int* __restrict__ dst,
    uint* __restrict__ idxv, uint* __restrict__ cnt, uint* __restrict__ ovf,
    uint* __restrict__ nact, uint* __restrict__ activev)
{
    int b = blockIdx.x;
    int tid = threadIdx.x;
    if (b < 512) {
        int idx = b * 256 + tid;                 // 0 .. 131071
        int j = idx & 7;
        int l = (idx >> 3) & 63;
        int s = (idx >> 9) & 7;
        int t = idx >> 12;
        int n = t * 16 + (l & 15);
        int k = s * 32 + (l >> 4) * 8 + j;
        int half = k >> 7;
        int kk = k & 127;
        float v;
        if (n < 256) {
            v = half ? Whh[(size_t)n * 128 + kk] : Wih[(size_t)n * 128 + kk];
        } else if (n < 384) {
            v = half ? 0.0f : Wih[(size_t)n * 128 + kk];
        } else {
            v = half ? Whh[(size_t)(n - 128) * 128 + kk] : 0.0f;
        }
        wfg[idx] = f2bf(v);
    } else if (b < 768) {
        int idx = (b - 512) * 256 + tid;         // 0 .. 65535
        int j = idx & 7;
        int l = (idx >> 3) & 63;
        int s = (idx >> 9) & 15;
        int t = idx >> 13;
        int n = t * 16 + (l & 15);
        int k = s * 32 + (l >> 4) * 8 + j;
        float v = (k < RAW_DIM) ? msgW[(size_t)n * RAW_DIM + k] : 0.0f;
        wfm[idx] = f2bf(v);
    } else {
        int i = (b - 768) * 256 + tid;
        if (i < E_EDGES) {
            int s = src[i];
            int d = dst[i];
            uint rs = atomicAdd(&cnt[s], 1u);
            if (ACT && rs == 0u) {
                uint ppos = atomicAdd(nact, 1u);
                activev[ppos] = (uint)s;
            }
            if (rs < (uint)CAPX) {
                idxv[(size_t)s * CAPX + rs] = (uint)i;
            } else {
                uint o = atomicAdd(&ovf[0], 1u);
                if (o < OVF_MAX) { ovf[1 + 2 * o] = (uint)s; ovf[2 + 2 * o] = (uint)i; }
            }
            uint rd = atomicAdd(&cnt[d], 1u);
            if (ACT && rd == 0u) {
                uint ppos = atomicAdd(nact, 1u);
                activev[ppos] = (uint)d;
            }
            if (rd < (uint)CAPX) {
                idxv[(size_t)d * CAPX + rd] = (uint)i;
            } else {
                uint o = atomicAdd(&ovf[0], 1u);
                if (o < OVF_MAX) { ovf[1 + 2 * o] = (uint)d; ovf[2 + 2 * o] = (uint)i; }
            }
        }
    }
}

// ---------------------------------------------------------------------------
// Kernel A (f32 store): register-gather MFMA message MLP, NO atomics.
// (verbatim round-9/10 passing kernel)
// ---------------------------------------------------------------------------
#define MTE 32

__global__ __launch_bounds__(128, 2) void tgn_msg_f32(
    const float* __restrict__ memory,
    const float* __restrict__ last_update,
    const float* __restrict__ timestamps,
    const float* __restrict__ edge_features,
    const float* __restrict__ msg_b,
    const float* __restrict__ time_w,
    const float* __restrict__ time_b,
    const int*   __restrict__ src,
    const int*   __restrict__ dst,
    const short* __restrict__ wfm,
    float* __restrict__ msgf)
{
    const int tid  = threadIdx.x;
    const int wv   = tid >> 6;
    const int l    = tid & 63;
    const int lrow = l & 15;
    const int lkg  = l >> 4;
    const int e0   = blockIdx.x * MTE + wv * 16;
    const int e    = e0 + lrow;

    const int sid = src[e];
    const int did = dst[e];
    const float dt = timestamps[e] - last_update[sid];

    const float* srcm = memory        + (size_t)sid * 128 + lkg * 8;
    const float* dstm = memory        + (size_t)did * 128 + lkg * 8;
    const float* ef   = edge_features + (size_t)e   * 128 + lkg * 8;
    float4 bufS[8], bufD[8], bufE[8];
#pragma unroll
    for (int s = 0; s < 4; ++s) {
        bufS[2 * s]     = *reinterpret_cast<const float4*>(srcm + s * 32);
        bufS[2 * s + 1] = *reinterpret_cast<const float4*>(srcm + s * 32 + 4);
        bufD[2 * s]     = *reinterpret_cast<const float4*>(dstm + s * 32);
        bufD[2 * s + 1] = *reinterpret_cast<const float4*>(dstm + s * 32 + 4);
        bufE[2 * s]     = *reinterpret_cast<const float4*>(ef + s * 32);
        bufE[2 * s + 1] = *reinterpret_cast<const float4*>(ef + s * 32 + 4);
    }

    bf16x8 afr[16];
#pragma unroll
    for (int s = 12; s < 16; ++s) {
        int k0 = s * 32 + lkg * 8;
        float4 lo, hi;
#pragma unroll
        for (int j = 0; j < 8; ++j) {
            int k = k0 + j;
            float v = 0.0f;
            if (k < RAW_DIM) {
                int t = k - 384;
                v = __cosf(fmaf(dt, time_w[t], time_b[t]));
            }
            if (j < 4) (&lo.x)[j] = v; else (&hi.x)[j - 4] = v;
        }
        afr[s] = pack8(lo, hi);
    }

#pragma unroll
    for (int s = 0; s < 4; ++s) {
        afr[s]     = pack8(bufS[2 * s], bufS[2 * s + 1]);
        afr[4 + s] = pack8(bufD[2 * s], bufD[2 * s + 1]);
        afr[8 + s] = pack8(bufE[2 * s], bufE[2 * s + 1]);
    }

    f32x4 acc[8];
#pragma unroll
    for (int t = 0; t < 8; ++t) acc[t] = (f32x4){0.f, 0.f, 0.f, 0.f};

#pragma unroll
    for (int s = 0; s < 16; ++s) {
#pragma unroll
        for (int t = 0; t < 8; ++t) {
            bf16x8 B = *reinterpret_cast<const bf16x8*>(
                &wfm[(size_t)(((t * 16 + s) * 64) + l) * 8]);
            acc[t] = __builtin_amdgcn_mfma_f32_16x16x32_bf16(afr[s], B, acc[t], 0, 0, 0);
        }
    }

#pragma unroll
    for (int r = 0; r < 4; ++r) {
        int erow = e0 + lkg * 4 + r;
        float* orow = msgf + (size_t)erow * 128;
#pragma unroll
        for (int t = 0; t < 8; ++t) {
            int j = t * 16 + lrow;
            orow[j] = acc[t][r] + msg_b[j];
        }
    }
}

// ---------------------------------------------------------------------------
// Kernel B tier-1 (compacted): blocks [0,nab) run MFMA GRU on active nodes
// via activev indirection; remaining blocks stream-copy inactive rows.
// CAP=12 (16B-aligned slot rows), indices preloaded as 3x uint4.
// ---------------------------------------------------------------------------
#define GNT 32
#define GRID_GEMM ((N_NODES + GNT - 1) / GNT)   // 6250
#define COPY_EXTRA 64

__global__ __launch_bounds__(256, 4) void tgn_gru_act(
    const float* __restrict__ memory,
    const float* __restrict__ last_update,
    const float* __restrict__ timestamps,
    const float* __restrict__ b_ih,
    const float* __restrict__ b_hh,
    const short* __restrict__ wfrag,
    const float* __restrict__ msgf,
    const uint*  __restrict__ idxv,
    const uint*  __restrict__ cnt,
    const uint*  __restrict__ ovf,
    const uint*  __restrict__ nactv,
    const uint*  __restrict__ activev,
    float* __restrict__ out)
{
    __shared__ short X[GNT][264];
    __shared__ float cntS[GNT];
    __shared__ uint  anS[GNT];

    const int tid = threadIdx.x;
    const uint nact = nactv[0];
    const uint nab  = (nact + GNT - 1) / GNT;
    const int  bid  = blockIdx.x;

    if (bid >= (int)nab) {
        // ---- copy path: sweep a contiguous node range, copy cnt==0 rows ----
        const uint ncb = (uint)gridDim.x - nab;
        const uint cb  = (uint)bid - nab;
        const uint lo = (uint)(((unsigned long long)N_NODES * cb) / ncb);
        const uint hi = (uint)(((unsigned long long)N_NODES * (cb + 1)) / ncb);
        const int  sub = tid & 31;            // 32 threads per node
        for (uint base = lo; base < hi; base += 8) {
            uint node = base + (uint)(tid >> 5);
            if (node < hi && cnt[node] == 0u) {
                int c4 = sub * 4;
                *reinterpret_cast<float4*>(&out[(size_t)node * 128 + c4]) =
                    *reinterpret_cast<const float4*>(&memory[(size_t)node * 128 + c4]);
                if (sub == 0)
                    out[(size_t)N_NODES * 128 + node] = last_update[node];
            }
        }
        return;
    }

    // ---- GEMM path on compacted active nodes ----
    const int n0 = bid * GNT;
    if (tid < GNT) {
        uint a = ((uint)(n0 + tid) < nact) ? activev[n0 + tid] : INVALID_NODE;
        anS[tid] = a;
    }
    __syncthreads();

    const int  nloc  = tid >> 3;
    const int  p     = tid & 7;
    const uint anode = anS[nloc];
    const bool valid = (anode != INVALID_NODE);
    const uint c     = valid ? cnt[anode] : 0u;
    if (p == 0) cntS[nloc] = (float)c;

    // stage memory rows -> X[:, 128:256]
#pragma unroll
    for (int it = 0; it < 4; ++it) {
        int i = tid + it * 256;
        int m = i >> 5;
        int c4 = (i & 31) * 4;
        uint an = anS[m];
        uint rn = (an == INVALID_NODE) ? 0u : an;
        float4 mv = *reinterpret_cast<const float4*>(&memory[(size_t)rn * 128 + c4]);
        uint2 u = {cvtpk(mv.x, mv.y), cvtpk(mv.z, mv.w)};
        *reinterpret_cast<uint2*>(&X[m][128 + c4]) = u;
    }

    // gather-aggregate agg -> X[:, 0:128]; 8 threads/node, 16 dims each
    {
        float a[16];
#pragma unroll
        for (int q = 0; q < 16; ++q) a[q] = 0.0f;
        const uint cm = (c < 12u) ? c : 12u;
        if (cm > 0u) {
            const uint* ip = idxv + (size_t)anode * 12;
            uint4 i0 = *reinterpret_cast<const uint4*>(ip);
            uint4 i1 = {0, 0, 0, 0}, i2 = {0, 0, 0, 0};
            if (cm > 4u) i1 = *reinterpret_cast<const uint4*>(ip + 4);
            if (cm > 8u) i2 = *reinterpret_cast<const uint4*>(ip + 8);
            uint idxs[12];
            idxs[0] = i0.x; idxs[1] = i0.y; idxs[2]  = i0.z; idxs[3]  = i0.w;
            idxs[4] = i1.x; idxs[5] = i1.y; idxs[6]  = i1.z; idxs[7]  = i1.w;
            idxs[8] = i2.x; idxs[9] = i2.y; idxs[10] = i2.z; idxs[11] = i2.w;
#pragma unroll
            for (int i = 0; i < 12; ++i) {
                if ((uint)i < cm) {
                    const float* row = msgf + (size_t)idxs[i] * 128 + p * 16;
                    float4 v0 = *reinterpret_cast<const float4*>(row);
                    float4 v1 = *reinterpret_cast<const float4*>(row + 4);
                    float4 v2 = *reinterpret_cast<const float4*>(row + 8);
                    float4 v3 = *reinterpret_cast<const float4*>(row + 12);
                    a[0] += v0.x;  a[1] += v0.y;  a[2]  += v0.z;  a[3]  += v0.w;
                    a[4] += v1.x;  a[5] += v1.y;  a[6]  += v1.z;  a[7]  += v1.w;
                    a[8] += v2.x;  a[9] += v2.y;  a[10] += v2.z;  a[11] += v2.w;
                    a[12] += v3.x; a[13] += v3.y; a[14] += v3.z;  a[15] += v3.w;
                }
            }
        }
        if (c > 12u) {                         // rare: scan overflow list
            uint L = ovf[0];
            if (L > OVF_MAX) L = OVF_MAX;
            for (uint i = 0; i < L; ++i) {
                if (ovf[1 + 2 * i] == anode) {
                    uint eid = ovf[2 + 2 * i];
                    const float* row = msgf + (size_t)eid * 128 + p * 16;
                    float4 v0 = *reinterpret_cast<const float4*>(row);
                    float4 v1 = *reinterpret_cast<const float4*>(row + 4);
                    float4 v2 = *reinterpret_cast<const float4*>(row + 8);
                    float4 v3 = *reinterpret_cast<const float4*>(row + 12);
                    a[0] += v0.x;  a[1] += v0.y;  a[2]  += v0.z;  a[3]  += v0.w;
                    a[4] += v1.x;  a[5] += v1.y;  a[6]  += v1.z;  a[7]  += v1.w;
                    a[8] += v2.x;  a[9] += v2.y;  a[10] += v2.z;  a[11] += v2.w;
                    a[12] += v3.x; a[13] += v3.y; a[14] += v3.z;  a[15] += v3.w;
                }
            }
        }
        float inv = (c > 0u) ? (1.0f / (float)c) : 0.0f;
#pragma unroll
        for (int q = 0; q < 16; ++q) a[q] *= inv;
        float4 A0 = {a[0], a[1], a[2], a[3]};
        float4 A1 = {a[4], a[5], a[6], a[7]};
        float4 A2 = {a[8], a[9], a[10], a[11]};
        float4 A3 = {a[12], a[13], a[14], a[15]};
        *reinterpret_cast<bf16x8*>(&X[nloc][p * 16])     = pack8(A0, A1);
        *reinterpret_cast<bf16x8*>(&X[nloc][p * 16 + 8]) = pack8(A2, A3);
    }
    __syncthreads();

    const int w    = tid >> 6;
    const int l    = tid & 63;
    const int lrow = l & 15;
    const int lkg  = l >> 4;

    f32x4 acc[4][2][2];   // [quadrant][jt][mt]
#pragma unroll
    for (int q = 0; q < 4; q++)
#pragma unroll
        for (int jt = 0; jt < 2; jt++)
#pragma unroll
            for (int mt = 0; mt < 2; mt++)
                acc[q][jt][mt] = (f32x4){0.f, 0.f, 0.f, 0.f};

    for (int s = 0; s < 8; ++s) {
        bf16x8 A[2];
#pragma unroll
        for (int mt = 0; mt < 2; ++mt)
            A[mt] = *reinterpret_cast<const bf16x8*>(&X[mt * 16 + lrow][s * 32 + lkg * 8]);
#pragma unroll
        for (int q = 0; q < 4; ++q)
#pragma unroll
            for (int jt = 0; jt < 2; ++jt) {
                int t = q * 8 + w * 2 + jt;
                bf16x8 B = *reinterpret_cast<const bf16x8*>(&wfrag[(size_t)(((t * 8 + s) * 64) + l) * 8]);
#pragma unroll
                for (int mt = 0; mt < 2; ++mt)
                    acc[q][jt][mt] = __builtin_amdgcn_mfma_f32_16x16x32_bf16(
                        A[mt], B, acc[q][jt][mt], 0, 0, 0);
            }
    }

    const float ts0 = timestamps[0];

#pragma unroll
    for (int jt = 0; jt < 2; ++jt) {
        int j = w * 32 + jt * 16 + lrow;
        float br  = b_ih[j]       + b_hh[j];
        float bz  = b_ih[128 + j] + b_hh[128 + j];
        float bin = b_ih[256 + j];
        float bhn = b_hh[256 + j];
#pragma unroll
        for (int mt = 0; mt < 2; ++mt) {
#pragma unroll
            for (int r = 0; r < 4; ++r) {
                int mloc = mt * 16 + lkg * 4 + r;
                uint an = anS[mloc];
                if (an != INVALID_NODE) {
                    float rg  = acc[0][jt][mt][r] + br;
                    float zg  = acc[1][jt][mt][r] + bz;
                    float ing = acc[2][jt][mt][r] + bin;
                    float hng = acc[3][jt][mt][r] + bhn;
                    float rr = fsigmoid(rg);
                    float zz = fsigmoid(zg);
                    float nn = ftanh(ing + rr * hng);
                    float mv = bf2f((unsigned short)X[mloc][128 + j]);
                    float h  = (1.0f - zz) * nn + zz * mv;
                    out[(size_t)an * 128 + j] = h;
                }
            }
        }
    }

    if (tid < GNT) {
        uint an = anS[tid];
        if (an != INVALID_NODE)
            out[(size_t)N_NODES * 128 + an] = ts0;
    }
}

// ---------------------------------------------------------------------------
// Kernel B tier-2 (round-10 proven, CAP=10, full node range)
// ---------------------------------------------------------------------------
template<int CAPX>
__global__ __launch_bounds__(256, 4) void tgn_gru_f32(
    const float* __restrict__ memory,
    const float* __restrict__ last_update,
    const float* __restrict__ timestamps,
    const float* __restrict__ b_ih,
    const float* __restrict__ b_hh,
    const short* __restrict__ wfrag,
    const float* __restrict__ msgf,
    const uint*  __restrict__ idxv,
    const uint*  __restrict__ cnt,
    const uint*  __restrict__ ovf,
    float* __restrict__ out)
{
    __shared__ short X[GNT][264];
    __shared__ float cntS[GNT];

    const int tid = threadIdx.x;
    const int n0 = blockIdx.x * GNT;

    const int nloc = tid >> 3;
    const int p    = tid & 7;
    const int node = n0 + nloc;

    const uint c = cnt[node];
    if (p == 0) cntS[nloc] = (float)c;

#pragma unroll
    for (int it = 0; it < 4; ++it) {
        int i = tid + it * 256;
        int m = i >> 5;
        int c4 = (i & 31) * 4;
        float4 mv = *reinterpret_cast<const float4*>(&memory[(size_t)(n0 + m) * 128 + c4]);
        uint2 u = {cvtpk(mv.x, mv.y), cvtpk(mv.z, mv.w)};
        *reinterpret_cast<uint2*>(&X[m][128 + c4]) = u;
    }

    {
        float a[16];
#pragma unroll
        for (int q = 0; q < 16; ++q) a[q] = 0.0f;
        uint cm = (c < (uint)CAPX) ? c : (uint)CAPX;
        for (uint i = 0; i < cm; ++i) {
            uint eid = idxv[(size_t)node * CAPX + i];
            const float* row = msgf + (size_t)eid * 128 + p * 16;
            float4 v0 = *reinterpret_cast<const float4*>(row);
            float4 v1 = *reinterpret_cast<const float4*>(row + 4);
            float4 v2 = *reinterpret_cast<const float4*>(row + 8);
            float4 v3 = *reinterpret_cast<const float4*>(row + 12);
            a[0] += v0.x;  a[1] += v0.y;  a[2]  += v0.z;  a[3]  += v0.w;
            a[4] += v1.x;  a[5] += v1.y;  a[6]  += v1.z;  a[7]  += v1.w;
            a[8] += v2.x;  a[9] += v2.y;  a[10] += v2.z;  a[11] += v2.w;
            a[12] += v3.x; a[13] += v3.y; a[14] += v3.z;  a[15] += v3.w;
        }
        if (c > (uint)CAPX) {
            uint L = ovf[0];
            if (L > OVF_MAX) L = OVF_MAX;
            for (uint i = 0; i < L; ++i) {
                if (ovf[1 + 2 * i] == (uint)node) {
                    uint eid = ovf[2 + 2 * i];
                    const float* row = msgf + (size_t)eid * 128 + p * 16;
                    float4 v0 = *reinterpret_cast<const float4*>(row);
                    float4 v1 = *reinterpret_cast<const float4*>(row + 4);
                    float4 v2 = *reinterpret_cast<const float4*>(row + 8);
                    float4 v3 = *reinterpret_cast<const float4*>(row + 12);
                    a[0] += v0.x;  a[1] += v0.y;  a[2]  += v0.z;  a[3]  += v0.w;
                    a[4] += v1.x;  a[5] += v1.y;  a[6]  += v1.z;  a[7]  += v1.w;
                    a[8] += v2.x;  a[9] += v2.y;  a[10] += v2.z;  a[11] += v2.w;
                    a[12] += v3.x; a[13] += v3.y; a[14] += v3.z;  a[15] += v3.w;
                }
            }
        }
        float inv = (c > 0) ? (1.0f / (float)c) : 0.0f;
#pragma unroll
        for (int q = 0; q < 16; ++q) a[q] *= inv;
        float4 A0 = {a[0], a[1], a[2], a[3]};
        float4 A1 = {a[4], a[5], a[6], a[7]};
        float4 A2 = {a[8], a[9], a[10], a[11]};
        float4 A3 = {a[12], a[13], a[14], a[15]};
        *reinterpret_cast<bf16x8*>(&X[nloc][p * 16])     = pack8(A0, A1);
        *reinterpret_cast<bf16x8*>(&X[nloc][p * 16 + 8]) = pack8(A2, A3);
    }
    __syncthreads();

    const int w    = tid >> 6;
    const int l    = tid & 63;
    const int lrow = l & 15;
    const int lkg  = l >> 4;

    f32x4 acc[4][2][2];
#pragma unroll
    for (int q = 0; q < 4; q++)
#pragma unroll
        for (int jt = 0; jt < 2; jt++)
#pragma unroll
            for (int mt = 0; mt < 2; mt++)
                acc[q][jt][mt] = (f32x4){0.f, 0.f, 0.f, 0.f};

    for (int s = 0; s < 8; ++s) {
        bf16x8 A[2];
#pragma unroll
        for (int mt = 0; mt < 2; ++mt)
            A[mt] = *reinterpret_cast<const bf16x8*>(&X[mt * 16 + lrow][s * 32 + lkg * 8]);
#pragma unroll
        for (int q = 0; q < 4; ++q)
#pragma unroll
            for (int jt = 0; jt < 2; ++jt) {
                int t = q * 8 + w * 2 + jt;
                bf16x8 B = *reinterpret_cast<const bf16x8*>(&wfrag[(size_t)(((t * 8 + s) * 64) + l) * 8]);
#pragma unroll
                for (int mt = 0; mt < 2; ++mt)
                    acc[q][jt][mt] = __builtin_amdgcn_mfma_f32_16x16x32_bf16(
                        A[mt], B, acc[q][jt][mt], 0, 0, 0);
            }
    }

    const float ts0 = timestamps[0];

#pragma unroll
    for (int jt = 0; jt < 2; ++jt) {
        int j = w * 32 + jt * 16 + lrow;
        float br  = b_ih[j]       + b_hh[j];
        float bz  = b_ih[128 + j] + b_hh[128 + j];
        float bin = b_ih[256 + j];
        float bhn = b_hh[256 + j];
#pragma unroll
        for (int mt = 0; mt < 2; ++mt) {
#pragma unroll
            for (int r = 0; r < 4; ++r) {
                int mloc = mt * 16 + lkg * 4 + r;
                int nodew = n0 + mloc;
                float rg  = acc[0][jt][mt][r] + br;
                float zg  = acc[1][jt][mt][r] + bz;
                float ing = acc[2][jt][mt][r] + bin;
                float hng = acc[3][jt][mt][r] + bhn;
                float rr = fsigmoid(rg);
                float zz = fsigmoid(zg);
                float nn = ftanh(ing + rr * hng);
                float mv = bf2f((unsigned short)X[mloc][128 + j]);
                float h  = (1.0f - zz) * nn + zz * mv;
                out[(size_t)nodew * 128 + j] = (cntS[mloc] > 0.0f) ? h : mv;
            }
        }
    }

    if (tid < GNT) {
        int noded = n0 + tid;
        out[(size_t)N_NODES * 128 + noded] = (cntS[tid] > 0.0f) ? ts0 : last_update[noded];
    }
}

// ---------------------------------------------------------------------------
// Tier-3 fallback (round-7 proven): f32 atomics via d_out.
// ---------------------------------------------------------------------------
#define TE 32

__global__ __launch_bounds__(256, 2) void tgn_msg_mfma(
    const float* __restrict__ memory,
    const float* __restrict__ last_update,
    const float* __restrict__ timestamps,
    const float* __restrict__ edge_features,
    const float* __restrict__ msg_b,
    const float* __restrict__ time_w,
    const float* __restrict__ time_b,
    const int*   __restrict__ src,
    const int*   __restrict__ dst,
    const short* __restrict__ wfm,
    float* __restrict__ sums,
    float* __restrict__ counts)
{
    __shared__ short X[TE][520];
    __shared__ int   sid[TE];
    __shared__ int   did[TE];
    __shared__ float dtS[TE];

    const int tid = threadIdx.x;
    const int e0  = blockIdx.x * TE;

    if (tid < TE) {
        int s = src[e0 + tid];
        int d = dst[e0 + tid];
        sid[tid] = s;
        did[tid] = d;
        dtS[tid] = timestamps[e0 + tid] - last_update[s];
        atomicAdd(&counts[s], 1.0f);
        atomicAdd(&counts[d], 1.0f);
    }
    __syncthreads();

    for (int i = tid; i < TE * 128; i += 256) {
        int e = i >> 7;
        int c = (i & 127) * 4;
        float4 v;
        if (c < 128) {
            v = *reinterpret_cast<const float4*>(&memory[(size_t)sid[e] * 128 + c]);
        } else if (c < 256) {
            v = *reinterpret_cast<const float4*>(&memory[(size_t)did[e] * 128 + (c - 128)]);
        } else if (c < 384) {
            v = *reinterpret_cast<const float4*>(&edge_features[(size_t)(e0 + e) * 128 + (c - 256)]);
        } else if (c < 484) {
            float dt = dtS[e];
            int t = c - 384;
            v.x = __cosf(fmaf(dt, time_w[t + 0], time_b[t + 0]));
            v.y = __cosf(fmaf(dt, time_w[t + 1], time_b[t + 1]));
            v.z = __cosf(fmaf(dt, time_w[t + 2], time_b[t + 2]));
            v.w = __cosf(fmaf(dt, time_w[t + 3], time_b[t + 3]));
        } else {
            v.x = v.y = v.z = v.w = 0.0f;
        }
        short4 s4;
        s4.x = f2bf(v.x); s4.y = f2bf(v.y); s4.z = f2bf(v.z); s4.w = f2bf(v.w);
        *reinterpret_cast<short4*>(&X[e][c]) = s4;
    }
    __syncthreads();

    const int w    = tid >> 6;
    const int l    = tid & 63;
    const int lrow = l & 15;
    const int lkg  = l >> 4;
    const int et   = w & 1;
    const int nh   = w >> 1;

    f32x4 acc[4];
#pragma unroll
    for (int n = 0; n < 4; n++) acc[n] = (f32x4){0.f, 0.f, 0.f, 0.f};

#pragma unroll 4
    for (int s = 0; s < 16; ++s) {
        bf16x8 A = *reinterpret_cast<const bf16x8*>(&X[et * 16 + lrow][s * 32 + lkg * 8]);
#pragma unroll
        for (int ntl = 0; ntl < 4; ++ntl) {
            int t = nh * 4 + ntl;
            bf16x8 B = *reinterpret_cast<const bf16x8*>(&wfm[(size_t)(((t * 16 + s) * 64) + l) * 8]);
            acc[ntl] = __builtin_amdgcn_mfma_f32_16x16x32_bf16(A, B, acc[ntl], 0, 0, 0);
        }
    }

#pragma unroll
    for (int ntl = 0; ntl < 4; ++ntl) {
        int j = nh * 64 + ntl * 16 + lrow;
        float bias = msg_b[j];
#pragma unroll
        for (int r = 0; r < 4; ++r) {
            int el = et * 16 + lkg * 4 + r;
            float m = acc[ntl][r] + bias;
            atomicAdd(&sums[(size_t)sid[el] * 128 + j], m);
            atomicAdd(&sums[(size_t)did[el] * 128 + j], m);
        }
    }
}

__global__ __launch_bounds__(256, 3) void tgn_gru_mfma(
    const float* __restrict__ memory,
    const float* __restrict__ last_update,
    const float* __restrict__ timestamps,
    const float* __restrict__ b_ih,
    const float* __restrict__ b_hh,
    const short* __restrict__ wfrag,
    float* __restrict__ out)
{
    __shared__ short X[GNT][264];
    __shared__ float cntS[GNT];

    const int tid = threadIdx.x;
    const int n0 = blockIdx.x * GNT;
    const float* sums   = out;
    const float* counts = out + (size_t)N_NODES * 128;

    if (tid < GNT) cntS[tid] = counts[n0 + tid];
    __syncthreads();

    for (int i = tid; i < GNT * 32; i += 256) {
        int m = i >> 5;
        int c = (i & 31) * 4;
        float inv = 1.0f / fmaxf(cntS[m], 1.0f);
        float4 v = *reinterpret_cast<const float4*>(&sums[(size_t)(n0 + m) * 128 + c]);
        short4 a4;
        a4.x = f2bf(v.x * inv); a4.y = f2bf(v.y * inv);
        a4.z = f2bf(v.z * inv); a4.w = f2bf(v.w * inv);
        *reinterpret_cast<short4*>(&X[m][c]) = a4;
        float4 mv = *reinterpret_cast<const float4*>(&memory[(size_t)(n0 + m) * 128 + c]);
        short4 m4;
        m4.x = f2bf(mv.x); m4.y = f2bf(mv.y); m4.z = f2bf(mv.z); m4.w = f2bf(mv.w);
        *reinterpret_cast<short4*>(&X[m][128 + c]) = m4;
    }
    __syncthreads();

    const int w    = tid >> 6;
    const int l    = tid & 63;
    const int lrow = l & 15;
    const int lkg  = l >> 4;

    f32x4 acc[4][2][2];
#pragma unroll
    for (int q = 0; q < 4; q++)
#pragma unroll
        for (int jt = 0; jt < 2; jt++)
#pragma unroll
            for (int mt = 0; mt < 2; mt++)
                acc[q][jt][mt] = (f32x4){0.f, 0.f, 0.f, 0.f};

    for (int s = 0; s < 8; ++s) {
        bf16x8 A[2];
#pragma unroll
        for (int mt = 0; mt < 2; ++mt)
            A[mt] = *reinterpret_cast<const bf16x8*>(&X[mt * 16 + lrow][s * 32 + lkg * 8]);
#pragma unroll
        for (int q = 0; q < 4; ++q)
#pragma unroll
            for (int jt = 0; jt < 2; ++jt) {
                int t = q * 8 + w * 2 + jt;
                bf16x8 B = *reinterpret_cast<const bf16x8*>(&wfrag[(size_t)(((t * 8 + s) * 64) + l) * 8]);
#pragma unroll
                for (int mt = 0; mt < 2; ++mt)
                    acc[q][jt][mt] = __builtin_amdgcn_mfma_f32_16x16x32_bf16(
                        A[mt], B, acc[q][jt][mt], 0, 0, 0);
            }
    }

    const float ts0 = timestamps[0];
#pragma unroll
    for (int jt = 0; jt < 2; ++jt) {
        int j = w * 32 + jt * 16 + lrow;
        float br  = b_ih[j]       + b_hh[j];
        float bz  = b_ih[128 + j] + b_hh[128 + j];
        float bin = b_ih[256 + j];
        float bhn = b_hh[256 + j];
#pragma unroll
        for (int mt = 0; mt < 2; ++mt) {
#pragma unroll
            for (int r = 0; r < 4; ++r) {
                int mloc = mt * 16 + lkg * 4 + r;
                int node = n0 + mloc;
                float rg  = acc[0][jt][mt][r] + br;
                float zg  = acc[1][jt][mt][r] + bz;
                float ing = acc[2][jt][mt][r] + bin;
                float hng = acc[3][jt][mt][r] + bhn;
                float rr = fsigmoid(rg);
                float zz = fsigmoid(zg);
                float nn = ftanh(ing + rr * hng);
                float mv = memory[(size_t)node * 128 + j];
                float h  = (1.0f - zz) * nn + zz * mv;
                out[(size_t)node * 128 + j] = (cntS[mloc] > 0.0f) ? h : mv;
            }
        }
    }
    if (tid < GNT) {
        int node = n0 + tid;
        out[(size_t)N_NODES * 128 + node] = (cntS[tid] > 0.0f) ? ts0 : last_update[node];
    }
}

// ---------------------------------------------------------------------------
extern "C" void kernel_launch(void* const* d_in, const int* in_sizes, int n_in,
                              void* d_out, int out_size, void* d_ws, size_t ws_size,
                              hipStream_t stream) {
    const float* memory        = (const float*)d_in[0];
    const float* last_update   = (const float*)d_in[1];
    const float* timestamps    = (const float*)d_in[2];
    const float* edge_features = (const float*)d_in[3];
    const float* msg_W         = (const float*)d_in[4];
    const float* msg_b         = (const float*)d_in[5];
    const float* gru_W_ih      = (const float*)d_in[6];
    const float* gru_W_hh      = (const float*)d_in[7];
    const float* gru_b_ih      = (const float*)d_in[8];
    const float* gru_b_hh      = (const float*)d_in[9];
    const float* time_w        = (const float*)d_in[10];
    const float* time_b        = (const float*)d_in[11];
    const int*   src           = (const int*)d_in[12];
    const int*   dst           = (const int*)d_in[13];

    float* out = (float*)d_out;
    char* ws = (char*)d_ws;

    const size_t OFF_WGRU = 0;                                   // 256 KB
    const size_t OFF_WMSG = 262144;                              // 128 KB
    const size_t OFF_MSGF = 393216;                              // E*128 f32
    const size_t SZ_MSGF  = (size_t)E_EDGES * 128 * 4;           // 51.2 MB

    // Tier-1 layout (compact, CAP=12)
    const size_t OFF_IDX1 = OFF_MSGF + SZ_MSGF;
    const size_t SZ_IDX1  = (size_t)N_NODES * 12 * 4;            // 9.6 MB
    const size_t OFF_CNT1 = OFF_IDX1 + SZ_IDX1;
    const size_t OFF_NACT = OFF_CNT1 + (size_t)N_NODES * 4;      // 16 B
    const size_t OFF_OVF1 = OFF_NACT + 16;
    const size_t OFF_ACT  = OFF_OVF1 + 4 + (size_t)OVF_MAX * 8;
    const size_t WS1      = OFF_ACT + (size_t)N_NODES * 4;

    // Tier-2 layout (round-10, CAP=10)
    const size_t OFF_IDX2 = OFF_MSGF + SZ_MSGF;
    const size_t SZ_IDX2  = (size_t)N_NODES * 10 * 4;            // 8 MB
    const size_t OFF_CNT2 = OFF_IDX2 + SZ_IDX2;
    const size_t OFF_OVF2 = OFF_CNT2 + (size_t)N_NODES * 4;
    const size_t WS2      = OFF_OVF2 + 4 + (size_t)OVF_MAX * 8;

    short* wfrag_gru = (short*)(ws + OFF_WGRU);
    short* wfrag_msg = (short*)(ws + OFF_WMSG);
    const int TICKET_BLOCKS = (E_EDGES + 255) / 256;             // 391

    if (ws_size >= WS1) {
        float* msgf  = (float*)(ws + OFF_MSGF);
        uint*  idxv  = (uint*)(ws + OFF_IDX1);
        uint*  cnt   = (uint*)(ws + OFF_CNT1);
        uint*  nactv = (uint*)(ws + OFF_NACT);
        uint*  ovf   = (uint*)(ws + OFF_OVF1);
        uint*  actv  = (uint*)(ws + OFF_ACT);

        // zero cnt + nact + ovf[0] (contiguous)
        hipMemsetAsync(ws + OFF_CNT1, 0, (size_t)N_NODES * 4 + 20, stream);

        tgn_setup<12, true><<<768 + TICKET_BLOCKS, 256, 0, stream>>>(
            gru_W_ih, gru_W_hh, wfrag_gru, msg_W, wfrag_msg,
            src, dst, idxv, cnt, ovf, nactv, actv);

        tgn_msg_f32<<<E_EDGES / MTE, 128, 0, stream>>>(
            memory, last_update, timestamps, edge_features, msg_b,
            time_w, time_b, src, dst, wfrag_msg, msgf);

        tgn_gru_act<<<GRID_GEMM + COPY_EXTRA, 256, 0, stream>>>(
            memory, last_update, timestamps, gru_b_ih, gru_b_hh, wfrag_gru,
            msgf, idxv, cnt, ovf, nactv, actv, out);
    } else if (ws_size >= WS2) {
        float* msgf = (float*)(ws + OFF_MSGF);
        uint*  idxv = (uint*)(ws + OFF_IDX2);
        uint*  cnt  = (uint*)(ws + OFF_CNT2);
        uint*  ovf  = (uint*)(ws + OFF_OVF2);

        hipMemsetAsync(ws + OFF_CNT2, 0, (size_t)N_NODES * 4 + 16, stream);

        tgn_setup<10, false><<<768 + TICKET_BLOCKS, 256, 0, stream>>>(
            gru_W_ih, gru_W_hh, wfrag_gru, msg_W, wfrag_msg,
            src, dst, idxv, cnt, ovf, nullptr, nullptr);

        tgn_msg_f32<<<E_EDGES / MTE, 128, 0, stream>>>(
            memory, last_update, timestamps, edge_features, msg_b,
            time_w, time_b, src, dst, wfrag_msg, msgf);

        tgn_gru_f32<10><<<N_NODES / GNT, 256, 0, stream>>>(
            memory, last_update, timestamps, gru_b_ih, gru_b_hh, wfrag_gru,
            msgf, idxv, cnt, ovf, out);
    } else {
        hipMemsetAsync(d_out, 0, (size_t)out_size * sizeof(float), stream);
        float* sums   = out;
        float* counts = out + (size_t)N_NODES * 128;

        tgn_setup<10, false><<<768, 256, 0, stream>>>(
            gru_W_ih, gru_W_hh, wfrag_gru, msg_W, wfrag_msg,
            src, dst, nullptr, nullptr, nullptr, nullptr, nullptr);

        tgn_msg_mfma<<<E_EDGES / TE, 256, 0, stream>>>(
            memory, last_update, timestamps, edge_features, msg_b,
            time_w, time_b, src, dst, wfrag_msg, sums, counts);

        tgn_gru_mfma<<<N_NODES / GNT, 256, 0, stream>>>(
            memory, last_update, timestamps, gru_b_ih, gru_b_hh, wfrag_gru, out);
    }
}

// Round 13
// 243.094 us; speedup vs baseline: 1.1456x; 1.1456x over previous
//
#include <hip/hip_runtime.h>
#include <math.h>

#define N_NODES 200000
#define E_EDGES 100000
#define TIME_DIM 100
#define RAW_DIM 484   // 128 + 128 + 128 + 100
#define CAP 12        // per-node direct slots (48B rows, 16B-aligned)
#define OVF_MAX 8192

typedef short  bf16x8 __attribute__((ext_vector_type(8)));
typedef float  f32x4  __attribute__((ext_vector_type(4)));
typedef unsigned int uint;

__device__ __forceinline__ short f2bf(float f) {
    unsigned u = __builtin_bit_cast(unsigned, f);
    u = (u + 0x7FFFu + ((u >> 16) & 1u)) >> 16;   // RNE
    return (short)u;
}
__device__ __forceinline__ float bf2f(unsigned short u) {
    return __builtin_bit_cast(float, ((unsigned)u) << 16);
}
__device__ __forceinline__ float fsigmoid(float x) {
    return __builtin_amdgcn_rcpf(1.0f + __expf(-x));
}
__device__ __forceinline__ float ftanh(float x) {
    float t = __expf(2.0f * x);
    return 1.0f - 2.0f * __builtin_amdgcn_rcpf(t + 1.0f);
}
__device__ __forceinline__ unsigned cvtpk(float a, float b) {
    unsigned r;
    asm("v_cvt_pk_bf16_f32 %0, %1, %2" : "=v"(r) : "v"(a), "v"(b));
    return r;
}
__device__ __forceinline__ bf16x8 pack8(float4 a, float4 b) {
    uint4 u = {cvtpk(a.x, a.y), cvtpk(a.z, a.w), cvtpk(b.x, b.y), cvtpk(b.z, b.w)};
    return __builtin_bit_cast(bf16x8, u);
}

// ---------------------------------------------------------------------------
// Setup: weight-fragment packs + ticket slot lists (STANDALONE — proven in
// r10/r11; fused-into-msg variants fail, see r6/r8/r12).
//   blocks [0,512)   : pack W_big[512][256] (GRU) -> wfg
//   blocks [512,768) : pack msg_W -> wfm (K padded to 512)
//   blocks [768,...) : tickets (cnt/ovf[0] pre-zeroed); skipped if idxv==null
// ---------------------------------------------------------------------------
__global__ __launch_bounds__(256) void tgn_setup(
    const float* __restrict__ Wih, const float* __restrict__ Whh,
    short* __restrict__ wfg,
    const float* __restrict__ msgW, short* __restrict__ wfm,
    const int* __restrict__ src, const int* __restrict__ dst,
    uint* __restrict__ idxv, uint* __restrict__ cnt, uint* __restrict__ ovf)
{
    int b = blockIdx.x;
    int tid = threadIdx.x;
    if (b < 512) {
        int idx = b * 256 + tid;                 // 0 .. 131071
        int j = idx & 7;
        int l = (idx >> 3) & 63;
        int s = (idx >> 9) & 7;
        int t = idx >> 12;
        int n = t * 16 + (l & 15);
        int k = s * 32 + (l >> 4) * 8 + j;
        int half = k >> 7;
        int kk = k & 127;
        float v;
        if (n < 256) {
            v = half ? Whh[(size_t)n * 128 + kk] : Wih[(size_t)n * 128 + kk];
        } else if (n < 384) {
            v = half ? 0.0f : Wih[(size_t)n * 128 + kk];
        } else {
            v = half ? Whh[(size_t)(n - 128) * 128 + kk] : 0.0f;
        }
        wfg[idx] = f2bf(v);
    } else if (b < 768) {
        int idx = (b - 512) * 256 + tid;         // 0 .. 65535
        int j = idx & 7;
        int l = (idx >> 3) & 63;
        int s = (idx >> 9) & 15;
        int t = idx >> 13;
        int n = t * 16 + (l & 15);
        int k = s * 32 + (l >> 4) * 8 + j;
        float v = (k < RAW_DIM) ? msgW[(size_t)n * RAW_DIM + k] : 0.0f;
        wfm[idx] = f2bf(v);
    } else {
        int i = (b - 768) * 256 + tid;
        if (i < E_EDGES) {
            int s = src[i];
            int d = dst[i];
            uint rs = atomicAdd(&cnt[s], 1u);
            if (rs < (uint)CAP) {
                idxv[(size_t)s * CAP + rs] = (uint)i;
            } else {
                uint o = atomicAdd(&ovf[0], 1u);
                if (o < OVF_MAX) { ovf[1 + 2 * o] = (uint)s; ovf[2 + 2 * o] = (uint)i; }
            }
            uint rd = atomicAdd(&cnt[d], 1u);
            if (rd < (uint)CAP) {
                idxv[(size_t)d * CAP + rd] = (uint)i;
            } else {
                uint o = atomicAdd(&ovf[0], 1u);
                if (o < OVF_MAX) { ovf[1 + 2 * o] = (uint)d; ovf[2 + 2 * o] = (uint)i; }
            }
        }
    }
}

// ---------------------------------------------------------------------------
// Kernel A (f32 store): register-gather MFMA message MLP, NO atomics.
// 128 threads = 2 waves; wave owns 16 edges x all 128 outputs.
// (verbatim round-9/10 passing kernel)
// ---------------------------------------------------------------------------
#define MTE 32

__global__ __launch_bounds__(128, 2) void tgn_msg_f32(
    const float* __restrict__ memory,
    const float* __restrict__ last_update,
    const float* __restrict__ timestamps,
    const float* __restrict__ edge_features,
    const float* __restrict__ msg_b,
    const float* __restrict__ time_w,
    const float* __restrict__ time_b,
    const int*   __restrict__ src,
    const int*   __restrict__ dst,
    const short* __restrict__ wfm,
    float* __restrict__ msgf)
{
    const int tid  = threadIdx.x;
    const int wv   = tid >> 6;
    const int l    = tid & 63;
    const int lrow = l & 15;
    const int lkg  = l >> 4;
    const int e0   = blockIdx.x * MTE + wv * 16;
    const int e    = e0 + lrow;

    const int sid = src[e];
    const int did = dst[e];
    const float dt = timestamps[e] - last_update[sid];

    const float* srcm = memory        + (size_t)sid * 128 + lkg * 8;
    const float* dstm = memory        + (size_t)did * 128 + lkg * 8;
    const float* ef   = edge_features + (size_t)e   * 128 + lkg * 8;
    float4 bufS[8], bufD[8], bufE[8];
#pragma unroll
    for (int s = 0; s < 4; ++s) {
        bufS[2 * s]     = *reinterpret_cast<const float4*>(srcm + s * 32);
        bufS[2 * s + 1] = *reinterpret_cast<const float4*>(srcm + s * 32 + 4);
        bufD[2 * s]     = *reinterpret_cast<const float4*>(dstm + s * 32);
        bufD[2 * s + 1] = *reinterpret_cast<const float4*>(dstm + s * 32 + 4);
        bufE[2 * s]     = *reinterpret_cast<const float4*>(ef + s * 32);
        bufE[2 * s + 1] = *reinterpret_cast<const float4*>(ef + s * 32 + 4);
    }

    bf16x8 afr[16];
#pragma unroll
    for (int s = 12; s < 16; ++s) {
        int k0 = s * 32 + lkg * 8;
        float4 lo, hi;
#pragma unroll
        for (int j = 0; j < 8; ++j) {
            int k = k0 + j;
            float v = 0.0f;
            if (k < RAW_DIM) {
                int t = k - 384;
                v = __cosf(fmaf(dt, time_w[t], time_b[t]));
            }
            if (j < 4) (&lo.x)[j] = v; else (&hi.x)[j - 4] = v;
        }
        afr[s] = pack8(lo, hi);
    }

#pragma unroll
    for (int s = 0; s < 4; ++s) {
        afr[s]     = pack8(bufS[2 * s], bufS[2 * s + 1]);
        afr[4 + s] = pack8(bufD[2 * s], bufD[2 * s + 1]);
        afr[8 + s] = pack8(bufE[2 * s], bufE[2 * s + 1]);
    }

    f32x4 acc[8];
#pragma unroll
    for (int t = 0; t < 8; ++t) acc[t] = (f32x4){0.f, 0.f, 0.f, 0.f};

#pragma unroll
    for (int s = 0; s < 16; ++s) {
#pragma unroll
        for (int t = 0; t < 8; ++t) {
            bf16x8 B = *reinterpret_cast<const bf16x8*>(
                &wfm[(size_t)(((t * 16 + s) * 64) + l) * 8]);
            acc[t] = __builtin_amdgcn_mfma_f32_16x16x32_bf16(afr[s], B, acc[t], 0, 0, 0);
        }
    }

#pragma unroll
    for (int r = 0; r < 4; ++r) {
        int erow = e0 + lkg * 4 + r;
        float* orow = msgf + (size_t)erow * 128;
#pragma unroll
        for (int t = 0; t < 8; ++t) {
            int j = t * 16 + lrow;
            orow[j] = acc[t][r] + msg_b[j];
        }
    }
}

// ---------------------------------------------------------------------------
// Kernel B: preloaded-idx gather (r11-proven) + f32 mean + MFMA GRU.
// Linear node mapping (32 nodes/block, r10-proven), 256 threads, 4 waves/EU.
// ---------------------------------------------------------------------------
#define GNT 32

__global__ __launch_bounds__(256, 4) void tgn_gru_f32(
    const float* __restrict__ memory,
    const float* __restrict__ last_update,
    const float* __restrict__ timestamps,
    const float* __restrict__ b_ih,
    const float* __restrict__ b_hh,
    const short* __restrict__ wfrag,
    const float* __restrict__ msgf,
    const uint*  __restrict__ idxv,
    const uint*  __restrict__ cnt,
    const uint*  __restrict__ ovf,
    float* __restrict__ out)
{
    __shared__ short X[GNT][264];
    __shared__ float cntS[GNT];

    const int tid = threadIdx.x;
    const int n0 = blockIdx.x * GNT;

    const int nloc = tid >> 3;
    const int p    = tid & 7;
    const int node = n0 + nloc;

    const uint c = cnt[node];
    if (p == 0) cntS[nloc] = (float)c;

    // stage memory -> X[:, 128:256] (independent coalesced streams)
#pragma unroll
    for (int it = 0; it < 4; ++it) {
        int i = tid + it * 256;
        int m = i >> 5;
        int c4 = (i & 31) * 4;
        float4 mv = *reinterpret_cast<const float4*>(&memory[(size_t)(n0 + m) * 128 + c4]);
        uint2 u = {cvtpk(mv.x, mv.y), cvtpk(mv.z, mv.w)};
        *reinterpret_cast<uint2*>(&X[m][128 + c4]) = u;
    }

    // gather-aggregate agg -> X[:, 0:128]; 8 threads/node, 16 dims each.
    // All CAP indices preloaded as 3x uint4 -> all row loads issue together.
    {
        float a[16];
#pragma unroll
        for (int q = 0; q < 16; ++q) a[q] = 0.0f;
        const uint cm = (c < (uint)CAP) ? c : (uint)CAP;
        if (cm > 0u) {
            const uint* ip = idxv + (size_t)node * CAP;
            uint4 i0 = *reinterpret_cast<const uint4*>(ip);
            uint4 i1 = {0, 0, 0, 0}, i2 = {0, 0, 0, 0};
            if (cm > 4u) i1 = *reinterpret_cast<const uint4*>(ip + 4);
            if (cm > 8u) i2 = *reinterpret_cast<const uint4*>(ip + 8);
            uint idxs[12];
            idxs[0] = i0.x; idxs[1] = i0.y; idxs[2]  = i0.z; idxs[3]  = i0.w;
            idxs[4] = i1.x; idxs[5] = i1.y; idxs[6]  = i1.z; idxs[7]  = i1.w;
            idxs[8] = i2.x; idxs[9] = i2.y; idxs[10] = i2.z; idxs[11] = i2.w;
#pragma unroll
            for (int i = 0; i < 12; ++i) {
                if ((uint)i < cm) {
                    const float* row = msgf + (size_t)idxs[i] * 128 + p * 16;
                    float4 v0 = *reinterpret_cast<const float4*>(row);
                    float4 v1 = *reinterpret_cast<const float4*>(row + 4);
                    float4 v2 = *reinterpret_cast<const float4*>(row + 8);
                    float4 v3 = *reinterpret_cast<const float4*>(row + 12);
                    a[0] += v0.x;  a[1] += v0.y;  a[2]  += v0.z;  a[3]  += v0.w;
                    a[4] += v1.x;  a[5] += v1.y;  a[6]  += v1.z;  a[7]  += v1.w;
                    a[8] += v2.x;  a[9] += v2.y;  a[10] += v2.z;  a[11] += v2.w;
                    a[12] += v3.x; a[13] += v3.y; a[14] += v3.z;  a[15] += v3.w;
                }
            }
        }
        if (c > (uint)CAP) {                   // rare: scan overflow list
            uint L = ovf[0];
            if (L > OVF_MAX) L = OVF_MAX;
            for (uint i = 0; i < L; ++i) {
                if (ovf[1 + 2 * i] == (uint)node) {
                    uint eid = ovf[2 + 2 * i];
                    const float* row = msgf + (size_t)eid * 128 + p * 16;
                    float4 v0 = *reinterpret_cast<const float4*>(row);
                    float4 v1 = *reinterpret_cast<const float4*>(row + 4);
                    float4 v2 = *reinterpret_cast<const float4*>(row + 8);
                    float4 v3 = *reinterpret_cast<const float4*>(row + 12);
                    a[0] += v0.x;  a[1] += v0.y;  a[2]  += v0.z;  a[3]  += v0.w;
                    a[4] += v1.x;  a[5] += v1.y;  a[6]  += v1.z;  a[7]  += v1.w;
                    a[8] += v2.x;  a[9] += v2.y;  a[10] += v2.z;  a[11] += v2.w;
                    a[12] += v3.x; a[13] += v3.y; a[14] += v3.z;  a[15] += v3.w;
                }
            }
        }
        float inv = (c > 0u) ? (1.0f / (float)c) : 0.0f;
#pragma unroll
        for (int q = 0; q < 16; ++q) a[q] *= inv;
        float4 A0 = {a[0], a[1], a[2], a[3]};
        float4 A1 = {a[4], a[5], a[6], a[7]};
        float4 A2 = {a[8], a[9], a[10], a[11]};
        float4 A3 = {a[12], a[13], a[14], a[15]};
        *reinterpret_cast<bf16x8*>(&X[nloc][p * 16])     = pack8(A0, A1);
        *reinterpret_cast<bf16x8*>(&X[nloc][p * 16 + 8]) = pack8(A2, A3);
    }
    __syncthreads();

    const int w    = tid >> 6;
    const int l    = tid & 63;
    const int lrow = l & 15;
    const int lkg  = l >> 4;

    f32x4 acc[4][2][2];   // [quadrant][jt][mt]
#pragma unroll
    for (int q = 0; q < 4; q++)
#pragma unroll
        for (int jt = 0; jt < 2; jt++)
#pragma unroll
            for (int mt = 0; mt < 2; mt++)
                acc[q][jt][mt] = (f32x4){0.f, 0.f, 0.f, 0.f};

    for (int s = 0; s < 8; ++s) {
        bf16x8 A[2];
#pragma unroll
        for (int mt = 0; mt < 2; ++mt)
            A[mt] = *reinterpret_cast<const bf16x8*>(&X[mt * 16 + lrow][s * 32 + lkg * 8]);
#pragma unroll
        for (int q = 0; q < 4; ++q)
#pragma unroll
            for (int jt = 0; jt < 2; ++jt) {
                int t = q * 8 + w * 2 + jt;
                bf16x8 B = *reinterpret_cast<const bf16x8*>(&wfrag[(size_t)(((t * 8 + s) * 64) + l) * 8]);
#pragma unroll
                for (int mt = 0; mt < 2; ++mt)
                    acc[q][jt][mt] = __builtin_amdgcn_mfma_f32_16x16x32_bf16(
                        A[mt], B, acc[q][jt][mt], 0, 0, 0);
            }
    }

    const float ts0 = timestamps[0];

#pragma unroll
    for (int jt = 0; jt < 2; ++jt) {
        int j = w * 32 + jt * 16 + lrow;
        float br  = b_ih[j]       + b_hh[j];
        float bz  = b_ih[128 + j] + b_hh[128 + j];
        float bin = b_ih[256 + j];
        float bhn = b_hh[256 + j];
#pragma unroll
        for (int mt = 0; mt < 2; ++mt) {
#pragma unroll
            for (int r = 0; r < 4; ++r) {
                int mloc = mt * 16 + lkg * 4 + r;
                int nodew = n0 + mloc;
                float rg  = acc[0][jt][mt][r] + br;
                float zg  = acc[1][jt][mt][r] + bz;
                float ing = acc[2][jt][mt][r] + bin;
                float hng = acc[3][jt][mt][r] + bhn;
                float rr = fsigmoid(rg);
                float zz = fsigmoid(zg);
                float nn = ftanh(ing + rr * hng);
                float mv = bf2f((unsigned short)X[mloc][128 + j]);
                float h  = (1.0f - zz) * nn + zz * mv;
                out[(size_t)nodew * 128 + j] = (cntS[mloc] > 0.0f) ? h : mv;
            }
        }
    }

    if (tid < GNT) {
        int noded = n0 + tid;
        out[(size_t)N_NODES * 128 + noded] = (cntS[tid] > 0.0f) ? ts0 : last_update[noded];
    }
}

// ---------------------------------------------------------------------------
// Fallback (round-7 proven): f32 atomics via d_out.
// ---------------------------------------------------------------------------
#define TE 32

__global__ __launch_bounds__(256, 2) void tgn_msg_mfma(
    const float* __restrict__ memory,
    const float* __restrict__ last_update,
    const float* __restrict__ timestamps,
    const float* __restrict__ edge_features,
    const float* __restrict__ msg_b,
    const float* __restrict__ time_w,
    const float* __restrict__ time_b,
    const int*   __restrict__ src,
    const int*   __restrict__ dst,
    const short* __restrict__ wfm,
    float* __restrict__ sums,
    float* __restrict__ counts)
{
    __shared__ short X[TE][520];
    __shared__ int   sid[TE];
    __shared__ int   did[TE];
    __shared__ float dtS[TE];

    const int tid = threadIdx.x;
    const int e0  = blockIdx.x * TE;

    if (tid < TE) {
        int s = src[e0 + tid];
        int d = dst[e0 + tid];
        sid[tid] = s;
        did[tid] = d;
        dtS[tid] = timestamps[e0 + tid] - last_update[s];
        atomicAdd(&counts[s], 1.0f);
        atomicAdd(&counts[d], 1.0f);
    }
    __syncthreads();

    for (int i = tid; i < TE * 128; i += 256) {
        int e = i >> 7;
        int c = (i & 127) * 4;
        float4 v;
        if (c < 128) {
            v = *reinterpret_cast<const float4*>(&memory[(size_t)sid[e] * 128 + c]);
        } else if (c < 256) {
            v = *reinterpret_cast<const float4*>(&memory[(size_t)did[e] * 128 + (c - 128)]);
        } else if (c < 384) {
            v = *reinterpret_cast<const float4*>(&edge_features[(size_t)(e0 + e) * 128 + (c - 256)]);
        } else if (c < 484) {
            float dt = dtS[e];
            int t = c - 384;
            v.x = __cosf(fmaf(dt, time_w[t + 0], time_b[t + 0]));
            v.y = __cosf(fmaf(dt, time_w[t + 1], time_b[t + 1]));
            v.z = __cosf(fmaf(dt, time_w[t + 2], time_b[t + 2]));
            v.w = __cosf(fmaf(dt, time_w[t + 3], time_b[t + 3]));
        } else {
            v.x = v.y = v.z = v.w = 0.0f;
        }
        short4 s4;
        s4.x = f2bf(v.x); s4.y = f2bf(v.y); s4.z = f2bf(v.z); s4.w = f2bf(v.w);
        *reinterpret_cast<short4*>(&X[e][c]) = s4;
    }
    __syncthreads();

    const int w    = tid >> 6;
    const int l    = tid & 63;
    const int lrow = l & 15;
    const int lkg  = l >> 4;
    const int et   = w & 1;
    const int nh   = w >> 1;

    f32x4 acc[4];
#pragma unroll
    for (int n = 0; n < 4; n++) acc[n] = (f32x4){0.f, 0.f, 0.f, 0.f};

#pragma unroll 4
    for (int s = 0; s < 16; ++s) {
        bf16x8 A = *reinterpret_cast<const bf16x8*>(&X[et * 16 + lrow][s * 32 + lkg * 8]);
#pragma unroll
        for (int ntl = 0; ntl < 4; ++ntl) {
            int t = nh * 4 + ntl;
            bf16x8 B = *reinterpret_cast<const bf16x8*>(&wfm[(size_t)(((t * 16 + s) * 64) + l) * 8]);
            acc[ntl] = __builtin_amdgcn_mfma_f32_16x16x32_bf16(A, B, acc[ntl], 0, 0, 0);
        }
    }

#pragma unroll
    for (int ntl = 0; ntl < 4; ++ntl) {
        int j = nh * 64 + ntl * 16 + lrow;
        float bias = msg_b[j];
#pragma unroll
        for (int r = 0; r < 4; ++r) {
            int el = et * 16 + lkg * 4 + r;
            float m = acc[ntl][r] + bias;
            atomicAdd(&sums[(size_t)sid[el] * 128 + j], m);
            atomicAdd(&sums[(size_t)did[el] * 128 + j], m);
        }
    }
}

__global__ __launch_bounds__(256, 3) void tgn_gru_mfma(
    const float* __restrict__ memory,
    const float* __restrict__ last_update,
    const float* __restrict__ timestamps,
    const float* __restrict__ b_ih,
    const float* __restrict__ b_hh,
    const short* __restrict__ wfrag,
    float* __restrict__ out)
{
    __shared__ short X[GNT][264];
    __shared__ float cntS[GNT];

    const int tid = threadIdx.x;
    const int n0 = blockIdx.x * GNT;
    const float* sums   = out;
    const float* counts = out + (size_t)N_NODES * 128;

    if (tid < GNT) cntS[tid] = counts[n0 + tid];
    __syncthreads();

    for (int i = tid; i < GNT * 32; i += 256) {
        int m = i >> 5;
        int c = (i & 31) * 4;
        float inv = 1.0f / fmaxf(cntS[m], 1.0f);
        float4 v = *reinterpret_cast<const float4*>(&sums[(size_t)(n0 + m) * 128 + c]);
        short4 a4;
        a4.x = f2bf(v.x * inv); a4.y = f2bf(v.y * inv);
        a4.z = f2bf(v.z * inv); a4.w = f2bf(v.w * inv);
        *reinterpret_cast<short4*>(&X[m][c]) = a4;
        float4 mv = *reinterpret_cast<const float4*>(&memory[(size_t)(n0 + m) * 128 + c]);
        short4 m4;
        m4.x = f2bf(mv.x); m4.y = f2bf(mv.y); m4.z = f2bf(mv.z); m4.w = f2bf(mv.w);
        *reinterpret_cast<short4*>(&X[m][128 + c]) = m4;
    }
    __syncthreads();

    const int w    = tid >> 6;
    const int l    = tid & 63;
    const int lrow = l & 15;
    const int lkg  = l >> 4;

    f32x4 acc[4][2][2];
#pragma unroll
    for (int q = 0; q < 4; q++)
#pragma unroll
        for (int jt = 0; jt < 2; jt++)
#pragma unroll
            for (int mt = 0; mt < 2; mt++)
                acc[q][jt][mt] = (f32x4){0.f, 0.f, 0.f, 0.f};

    for (int s = 0; s < 8; ++s) {
        bf16x8 A[2];
#pragma unroll
        for (int mt = 0; mt < 2; ++mt)
            A[mt] = *reinterpret_cast<const bf16x8*>(&X[mt * 16 + lrow][s * 32 + lkg * 8]);
#pragma unroll
        for (int q = 0; q < 4; ++q)
#pragma unroll
            for (int jt = 0; jt < 2; ++jt) {
                int t = q * 8 + w * 2 + jt;
                bf16x8 B = *reinterpret_cast<const bf16x8*>(&wfrag[(size_t)(((t * 8 + s) * 64) + l) * 8]);
#pragma unroll
                for (int mt = 0; mt < 2; ++mt)
                    acc[q][jt][mt] = __builtin_amdgcn_mfma_f32_16x16x32_bf16(
                        A[mt], B, acc[q][jt][mt], 0, 0, 0);
            }
    }

    const float ts0 = timestamps[0];
#pragma unroll
    for (int jt = 0; jt < 2; ++jt) {
        int j = w * 32 + jt * 16 + lrow;
        float br  = b_ih[j]       + b_hh[j];
        float bz  = b_ih[128 + j] + b_hh[128 + j];
        float bin = b_ih[256 + j];
        float bhn = b_hh[256 + j];
#pragma unroll
        for (int mt = 0; mt < 2; ++mt) {
#pragma unroll
            for (int r = 0; r < 4; ++r) {
                int mloc = mt * 16 + lkg * 4 + r;
                int node = n0 + mloc;
                float rg  = acc[0][jt][mt][r] + br;
                float zg  = acc[1][jt][mt][r] + bz;
                float ing = acc[2][jt][mt][r] + bin;
                float hng = acc[3][jt][mt][r] + bhn;
                float rr = fsigmoid(rg);
                float zz = fsigmoid(zg);
                float nn = ftanh(ing + rr * hng);
                float mv = memory[(size_t)node * 128 + j];
                float h  = (1.0f - zz) * nn + zz * mv;
                out[(size_t)node * 128 + j] = (cntS[mloc] > 0.0f) ? h : mv;
            }
        }
    }
    if (tid < GNT) {
        int node = n0 + tid;
        out[(size_t)N_NODES * 128 + node] = (cntS[tid] > 0.0f) ? ts0 : last_update[node];
    }
}

// ---------------------------------------------------------------------------
extern "C" void kernel_launch(void* const* d_in, const int* in_sizes, int n_in,
                              void* d_out, int out_size, void* d_ws, size_t ws_size,
                              hipStream_t stream) {
    const float* memory        = (const float*)d_in[0];
    const float* last_update   = (const float*)d_in[1];
    const float* timestamps    = (const float*)d_in[2];
    const float* edge_features = (const float*)d_in[3];
    const float* msg_W         = (const float*)d_in[4];
    const float* msg_b         = (const float*)d_in[5];
    const float* gru_W_ih      = (const float*)d_in[6];
    const float* gru_W_hh      = (const float*)d_in[7];
    const float* gru_b_ih      = (const float*)d_in[8];
    const float* gru_b_hh      = (const float*)d_in[9];
    const float* time_w        = (const float*)d_in[10];
    const float* time_b        = (const float*)d_in[11];
    const int*   src           = (const int*)d_in[12];
    const int*   dst           = (const int*)d_in[13];

    float* out = (float*)d_out;
    char* ws = (char*)d_ws;

    const size_t OFF_WGRU = 0;                                   // 256 KB
    const size_t OFF_WMSG = 262144;                              // 128 KB
    const size_t OFF_MSGF = 393216;                              // E*128 f32
    const size_t SZ_MSGF  = (size_t)E_EDGES * 128 * 4;           // 51.2 MB
    const size_t OFF_IDX  = OFF_MSGF + SZ_MSGF;                  // N*CAP u32
    const size_t SZ_IDX   = (size_t)N_NODES * CAP * 4;           // 9.6 MB
    const size_t OFF_CNT  = OFF_IDX + SZ_IDX;                    // N u32
    const size_t OFF_OVF  = OFF_CNT + (size_t)N_NODES * 4;
    const size_t WS_NEED  = OFF_OVF + 4 + (size_t)OVF_MAX * 8;

    short* wfrag_gru = (short*)(ws + OFF_WGRU);
    short* wfrag_msg = (short*)(ws + OFF_WMSG);
    const int TICKET_BLOCKS = (E_EDGES + 255) / 256;             // 391

    if (ws_size >= WS_NEED) {
        float* msgf = (float*)(ws + OFF_MSGF);
        uint*  idxv = (uint*)(ws + OFF_IDX);
        uint*  cnt  = (uint*)(ws + OFF_CNT);
        uint*  ovf  = (uint*)(ws + OFF_OVF);

        // zero cnt + ovf counter (contiguous, ~800 KB)
        hipMemsetAsync(ws + OFF_CNT, 0, (size_t)N_NODES * 4 + 16, stream);

        tgn_setup<<<768 + TICKET_BLOCKS, 256, 0, stream>>>(
            gru_W_ih, gru_W_hh, wfrag_gru, msg_W, wfrag_msg,
            src, dst, idxv, cnt, ovf);

        tgn_msg_f32<<<E_EDGES / MTE, 128, 0, stream>>>(
            memory, last_update, timestamps, edge_features, msg_b,
            time_w, time_b, src, dst, wfrag_msg, msgf);

        tgn_gru_f32<<<N_NODES / GNT, 256, 0, stream>>>(
            memory, last_update, timestamps, gru_b_ih, gru_b_hh, wfrag_gru,
            msgf, idxv, cnt, ovf, out);
    } else {
        hipMemsetAsync(d_out, 0, (size_t)out_size * sizeof(float), stream);
        float* sums   = out;
        float* counts = out + (size_t)N_NODES * 128;

        tgn_setup<<<768, 256, 0, stream>>>(
            gru_W_ih, gru_W_hh, wfrag_gru, msg_W, wfrag_msg,
            src, dst, nullptr, nullptr, nullptr);

        tgn_msg_mfma<<<E_EDGES / TE, 256, 0, stream>>>(
            memory, last_update, timestamps, edge_features, msg_b,
            time_w, time_b, src, dst, wfrag_msg, sums, counts);

        tgn_gru_mfma<<<N_NODES / GNT, 256, 0, stream>>>(
            memory, last_update, timestamps, gru_b_ih, gru_b_hh, wfrag_gru, out);
    }
}

// Round 14
// 236.493 us; speedup vs baseline: 1.1775x; 1.0279x over previous
//
#include <hip/hip_runtime.h>
#include <math.h>

#define N_NODES 200000
#define E_EDGES 100000
#define TIME_DIM 100
#define RAW_DIM 484   // 128 + 128 + 128 + 100
#define CAP 12        // per-node direct slots
#define OVF_MAX 8192

typedef short  bf16x8 __attribute__((ext_vector_type(8)));
typedef float  f32x4  __attribute__((ext_vector_type(4)));
typedef unsigned int uint;

__device__ __forceinline__ short f2bf(float f) {
    unsigned u = __builtin_bit_cast(unsigned, f);
    u = (u + 0x7FFFu + ((u >> 16) & 1u)) >> 16;   // RNE
    return (short)u;
}
__device__ __forceinline__ float bf2f(unsigned short u) {
    return __builtin_bit_cast(float, ((unsigned)u) << 16);
}
__device__ __forceinline__ float fsigmoid(float x) {
    return __builtin_amdgcn_rcpf(1.0f + __expf(-x));
}
__device__ __forceinline__ float ftanh(float x) {
    float t = __expf(2.0f * x);
    return 1.0f - 2.0f * __builtin_amdgcn_rcpf(t + 1.0f);
}
__device__ __forceinline__ unsigned cvtpk(float a, float b) {
    unsigned r;
    asm("v_cvt_pk_bf16_f32 %0, %1, %2" : "=v"(r) : "v"(a), "v"(b));
    return r;
}
__device__ __forceinline__ bf16x8 pack8(float4 a, float4 b) {
    uint4 u = {cvtpk(a.x, a.y), cvtpk(a.z, a.w), cvtpk(b.x, b.y), cvtpk(b.z, b.w)};
    return __builtin_bit_cast(bf16x8, u);
}

// ---------------------------------------------------------------------------
// Setup: weight-fragment packs + ticket slot lists (STANDALONE — proven in
// r10/r11/r13; fused-into-msg variants fail, see r6/r8/r12).
//   blocks [0,512)   : pack W_big[512][256] (GRU) -> wfg
//   blocks [512,768) : pack msg_W -> wfm (K padded to 512)
//   blocks [768,...) : tickets (cnt/ovf[0] pre-zeroed); skipped if idxv==null
// ---------------------------------------------------------------------------
__global__ __launch_bounds__(256) void tgn_setup(
    const float* __restrict__ Wih, const float* __restrict__ Whh,
    short* __restrict__ wfg,
    const float* __restrict__ msgW, short* __restrict__ wfm,
    const int* __restrict__ src, const int* __restrict__ dst,
    uint* __restrict__ idxv, uint* __restrict__ cnt, uint* __restrict__ ovf)
{
    int b = blockIdx.x;
    int tid = threadIdx.x;
    if (b < 512) {
        int idx = b * 256 + tid;                 // 0 .. 131071
        int j = idx & 7;
        int l = (idx >> 3) & 63;
        int s = (idx >> 9) & 7;
        int t = idx >> 12;
        int n = t * 16 + (l & 15);
        int k = s * 32 + (l >> 4) * 8 + j;
        int half = k >> 7;
        int kk = k & 127;
        float v;
        if (n < 256) {
            v = half ? Whh[(size_t)n * 128 + kk] : Wih[(size_t)n * 128 + kk];
        } else if (n < 384) {
            v = half ? 0.0f : Wih[(size_t)n * 128 + kk];
        } else {
            v = half ? Whh[(size_t)(n - 128) * 128 + kk] : 0.0f;
        }
        wfg[idx] = f2bf(v);
    } else if (b < 768) {
        int idx = (b - 512) * 256 + tid;         // 0 .. 65535
        int j = idx & 7;
        int l = (idx >> 3) & 63;
        int s = (idx >> 9) & 15;
        int t = idx >> 13;
        int n = t * 16 + (l & 15);
        int k = s * 32 + (l >> 4) * 8 + j;
        float v = (k < RAW_DIM) ? msgW[(size_t)n * RAW_DIM + k] : 0.0f;
        wfm[idx] = f2bf(v);
    } else {
        int i = (b - 768) * 256 + tid;
        if (i < E_EDGES) {
            int s = src[i];
            int d = dst[i];
            uint rs = atomicAdd(&cnt[s], 1u);
            if (rs < (uint)CAP) {
                idxv[(size_t)s * CAP + rs] = (uint)i;
            } else {
                uint o = atomicAdd(&ovf[0], 1u);
                if (o < OVF_MAX) { ovf[1 + 2 * o] = (uint)s; ovf[2 + 2 * o] = (uint)i; }
            }
            uint rd = atomicAdd(&cnt[d], 1u);
            if (rd < (uint)CAP) {
                idxv[(size_t)d * CAP + rd] = (uint)i;
            } else {
                uint o = atomicAdd(&ovf[0], 1u);
                if (o < OVF_MAX) { ovf[1 + 2 * o] = (uint)d; ovf[2 + 2 * o] = (uint)i; }
            }
        }
    }
}

// ---------------------------------------------------------------------------
// Kernel A (bf16 store): register-gather MFMA message MLP, NO atomics.
// 128 threads = 2 waves; wave owns 16 edges x all 128 outputs.
// Epilogue: shfl_xor pair (j,j+1) -> v_cvt_pk_bf16_f32 -> u32 store by even
// lanes (pairing construction proven in passing r4/r5 pk-atomic kernels).
// ---------------------------------------------------------------------------
#define MTE 32

__global__ __launch_bounds__(128, 2) void tgn_msg_bf(
    const float* __restrict__ memory,
    const float* __restrict__ last_update,
    const float* __restrict__ timestamps,
    const float* __restrict__ edge_features,
    const float* __restrict__ msg_b,
    const float* __restrict__ time_w,
    const float* __restrict__ time_b,
    const int*   __restrict__ src,
    const int*   __restrict__ dst,
    const short* __restrict__ wfm,
    short* __restrict__ msgb)
{
    const int tid  = threadIdx.x;
    const int wv   = tid >> 6;
    const int l    = tid & 63;
    const int lrow = l & 15;
    const int lkg  = l >> 4;
    const int e0   = blockIdx.x * MTE + wv * 16;
    const int e    = e0 + lrow;

    const int sid = src[e];
    const int did = dst[e];
    const float dt = timestamps[e] - last_update[sid];

    const float* srcm = memory        + (size_t)sid * 128 + lkg * 8;
    const float* dstm = memory        + (size_t)did * 128 + lkg * 8;
    const float* ef   = edge_features + (size_t)e   * 128 + lkg * 8;
    float4 bufS[8], bufD[8], bufE[8];
#pragma unroll
    for (int s = 0; s < 4; ++s) {
        bufS[2 * s]     = *reinterpret_cast<const float4*>(srcm + s * 32);
        bufS[2 * s + 1] = *reinterpret_cast<const float4*>(srcm + s * 32 + 4);
        bufD[2 * s]     = *reinterpret_cast<const float4*>(dstm + s * 32);
        bufD[2 * s + 1] = *reinterpret_cast<const float4*>(dstm + s * 32 + 4);
        bufE[2 * s]     = *reinterpret_cast<const float4*>(ef + s * 32);
        bufE[2 * s + 1] = *reinterpret_cast<const float4*>(ef + s * 32 + 4);
    }

    bf16x8 afr[16];
#pragma unroll
    for (int s = 12; s < 16; ++s) {
        int k0 = s * 32 + lkg * 8;
        float4 lo, hi;
#pragma unroll
        for (int j = 0; j < 8; ++j) {
            int k = k0 + j;
            float v = 0.0f;
            if (k < RAW_DIM) {
                int t = k - 384;
                v = __cosf(fmaf(dt, time_w[t], time_b[t]));
            }
            if (j < 4) (&lo.x)[j] = v; else (&hi.x)[j - 4] = v;
        }
        afr[s] = pack8(lo, hi);
    }

#pragma unroll
    for (int s = 0; s < 4; ++s) {
        afr[s]     = pack8(bufS[2 * s], bufS[2 * s + 1]);
        afr[4 + s] = pack8(bufD[2 * s], bufD[2 * s + 1]);
        afr[8 + s] = pack8(bufE[2 * s], bufE[2 * s + 1]);
    }

    f32x4 acc[8];
#pragma unroll
    for (int t = 0; t < 8; ++t) acc[t] = (f32x4){0.f, 0.f, 0.f, 0.f};

#pragma unroll
    for (int s = 0; s < 16; ++s) {
#pragma unroll
        for (int t = 0; t < 8; ++t) {
            bf16x8 B = *reinterpret_cast<const bf16x8*>(
                &wfm[(size_t)(((t * 16 + s) * 64) + l) * 8]);
            acc[t] = __builtin_amdgcn_mfma_f32_16x16x32_bf16(afr[s], B, acc[t], 0, 0, 0);
        }
    }

    // ---- epilogue: bias + paired bf16 store (even lanes write u32) ----
    const bool even = (l & 1) == 0;
#pragma unroll
    for (int r = 0; r < 4; ++r) {
        int erow = e0 + lkg * 4 + r;
#pragma unroll
        for (int t = 0; t < 8; ++t) {
            int j = t * 16 + lrow;
            float m = acc[t][r] + msg_b[j];
            float mo = __shfl_xor(m, 1);
            if (even) {
                unsigned pk = cvtpk(m, mo);   // low16 = col j, high16 = col j+1
                *reinterpret_cast<unsigned*>(&msgb[(size_t)erow * 128 + j]) = pk;
            }
        }
    }
}

// ---------------------------------------------------------------------------
// Kernel B: preloaded-idx bf16 gather + f32 mean + MFMA GRU.
// Linear node mapping (32 nodes/block), 256 threads, 4 waves/EU.
// ---------------------------------------------------------------------------
#define GNT 32

__global__ __launch_bounds__(256, 4) void tgn_gru_bf(
    const float* __restrict__ memory,
    const float* __restrict__ last_update,
    const float* __restrict__ timestamps,
    const float* __restrict__ b_ih,
    const float* __restrict__ b_hh,
    const short* __restrict__ wfrag,
    const short* __restrict__ msgb,
    const uint*  __restrict__ idxv,
    const uint*  __restrict__ cnt,
    const uint*  __restrict__ ovf,
    float* __restrict__ out)
{
    __shared__ short X[GNT][264];
    __shared__ float cntS[GNT];

    const int tid = threadIdx.x;
    const int n0 = blockIdx.x * GNT;

    const int nloc = tid >> 3;
    const int p    = tid & 7;
    const int node = n0 + nloc;

    const uint c = cnt[node];
    if (p == 0) cntS[nloc] = (float)c;

    // stage memory -> X[:, 128:256] (independent coalesced streams)
#pragma unroll
    for (int it = 0; it < 4; ++it) {
        int i = tid + it * 256;
        int m = i >> 5;
        int c4 = (i & 31) * 4;
        float4 mv = *reinterpret_cast<const float4*>(&memory[(size_t)(n0 + m) * 128 + c4]);
        uint2 u = {cvtpk(mv.x, mv.y), cvtpk(mv.z, mv.w)};
        *reinterpret_cast<uint2*>(&X[m][128 + c4]) = u;
    }

    // gather-aggregate agg -> X[:, 0:128]; 8 threads/node, 16 dims each.
    {
        float a[16];
#pragma unroll
        for (int q = 0; q < 16; ++q) a[q] = 0.0f;
        const uint cm = (c < (uint)CAP) ? c : (uint)CAP;
        if (cm > 0u) {
            const uint* ip = idxv + (size_t)node * CAP;
            uint4 i0 = *reinterpret_cast<const uint4*>(ip);
            uint4 i1 = {0, 0, 0, 0}, i2 = {0, 0, 0, 0};
            if (cm > 4u) i1 = *reinterpret_cast<const uint4*>(ip + 4);
            if (cm > 8u) i2 = *reinterpret_cast<const uint4*>(ip + 8);
            uint idxs[12];
            idxs[0] = i0.x; idxs[1] = i0.y; idxs[2]  = i0.z; idxs[3]  = i0.w;
            idxs[4] = i1.x; idxs[5] = i1.y; idxs[6]  = i1.z; idxs[7]  = i1.w;
            idxs[8] = i2.x; idxs[9] = i2.y; idxs[10] = i2.z; idxs[11] = i2.w;
#pragma unroll
            for (int i = 0; i < 12; ++i) {
                if ((uint)i < cm) {
                    const short* row = msgb + (size_t)idxs[i] * 128 + p * 16;
                    bf16x8 v0 = *reinterpret_cast<const bf16x8*>(row);
                    bf16x8 v1 = *reinterpret_cast<const bf16x8*>(row + 8);
#pragma unroll
                    for (int q = 0; q < 8; ++q) {
                        a[q]     += bf2f((unsigned short)v0[q]);
                        a[8 + q] += bf2f((unsigned short)v1[q]);
                    }
                }
            }
        }
        if (c > (uint)CAP) {                   // rare: scan overflow list
            uint L = ovf[0];
            if (L > OVF_MAX) L = OVF_MAX;
            for (uint i = 0; i < L; ++i) {
                if (ovf[1 + 2 * i] == (uint)node) {
                    uint eid = ovf[2 + 2 * i];
                    const short* row = msgb + (size_t)eid * 128 + p * 16;
                    bf16x8 v0 = *reinterpret_cast<const bf16x8*>(row);
                    bf16x8 v1 = *reinterpret_cast<const bf16x8*>(row + 8);
#pragma unroll
                    for (int q = 0; q < 8; ++q) {
                        a[q]     += bf2f((unsigned short)v0[q]);
                        a[8 + q] += bf2f((unsigned short)v1[q]);
                    }
                }
            }
        }
        float inv = (c > 0u) ? (1.0f / (float)c) : 0.0f;
#pragma unroll
        for (int q = 0; q < 16; ++q) a[q] *= inv;
        float4 A0 = {a[0], a[1], a[2], a[3]};
        float4 A1 = {a[4], a[5], a[6], a[7]};
        float4 A2 = {a[8], a[9], a[10], a[11]};
        float4 A3 = {a[12], a[13], a[14], a[15]};
        *reinterpret_cast<bf16x8*>(&X[nloc][p * 16])     = pack8(A0, A1);
        *reinterpret_cast<bf16x8*>(&X[nloc][p * 16 + 8]) = pack8(A2, A3);
    }
    __syncthreads();

    const int w    = tid >> 6;
    const int l    = tid & 63;
    const int lrow = l & 15;
    const int lkg  = l >> 4;

    f32x4 acc[4][2][2];   // [quadrant][jt][mt]
#pragma unroll
    for (int q = 0; q < 4; q++)
#pragma unroll
        for (int jt = 0; jt < 2; jt++)
#pragma unroll
            for (int mt = 0; mt < 2; mt++)
                acc[q][jt][mt] = (f32x4){0.f, 0.f, 0.f, 0.f};

    for (int s = 0; s < 8; ++s) {
        bf16x8 A[2];
#pragma unroll
        for (int mt = 0; mt < 2; ++mt)
            A[mt] = *reinterpret_cast<const bf16x8*>(&X[mt * 16 + lrow][s * 32 + lkg * 8]);
#pragma unroll
        for (int q = 0; q < 4; ++q)
#pragma unroll
            for (int jt = 0; jt < 2; ++jt) {
                int t = q * 8 + w * 2 + jt;
                bf16x8 B = *reinterpret_cast<const bf16x8*>(&wfrag[(size_t)(((t * 8 + s) * 64) + l) * 8]);
#pragma unroll
                for (int mt = 0; mt < 2; ++mt)
                    acc[q][jt][mt] = __builtin_amdgcn_mfma_f32_16x16x32_bf16(
                        A[mt], B, acc[q][jt][mt], 0, 0, 0);
            }
    }

    const float ts0 = timestamps[0];

#pragma unroll
    for (int jt = 0; jt < 2; ++jt) {
        int j = w * 32 + jt * 16 + lrow;
        float br  = b_ih[j]       + b_hh[j];
        float bz  = b_ih[128 + j] + b_hh[128 + j];
        float bin = b_ih[256 + j];
        float bhn = b_hh[256 + j];
#pragma unroll
        for (int mt = 0; mt < 2; ++mt) {
#pragma unroll
            for (int r = 0; r < 4; ++r) {
                int mloc = mt * 16 + lkg * 4 + r;
                int nodew = n0 + mloc;
                float rg  = acc[0][jt][mt][r] + br;
                float zg  = acc[1][jt][mt][r] + bz;
                float ing = acc[2][jt][mt][r] + bin;
                float hng = acc[3][jt][mt][r] + bhn;
                float rr = fsigmoid(rg);
                float zz = fsigmoid(zg);
                float nn = ftanh(ing + rr * hng);
                float mv = bf2f((unsigned short)X[mloc][128 + j]);
                float h  = (1.0f - zz) * nn + zz * mv;
                out[(size_t)nodew * 128 + j] = (cntS[mloc] > 0.0f) ? h : mv;
            }
        }
    }

    if (tid < GNT) {
        int noded = n0 + tid;
        out[(size_t)N_NODES * 128 + noded] = (cntS[tid] > 0.0f) ? ts0 : last_update[noded];
    }
}

// ---------------------------------------------------------------------------
// Fallback (round-7 proven): f32 atomics via d_out.
// ---------------------------------------------------------------------------
#define TE 32

__global__ __launch_bounds__(256, 2) void tgn_msg_mfma(
    const float* __restrict__ memory,
    const float* __restrict__ last_update,
    const float* __restrict__ timestamps,
    const float* __restrict__ edge_features,
    const float* __restrict__ msg_b,
    const float* __restrict__ time_w,
    const float* __restrict__ time_b,
    const int*   __restrict__ src,
    const int*   __restrict__ dst,
    const short* __restrict__ wfm,
    float* __restrict__ sums,
    float* __restrict__ counts)
{
    __shared__ short X[TE][520];
    __shared__ int   sid[TE];
    __shared__ int   did[TE];
    __shared__ float dtS[TE];

    const int tid = threadIdx.x;
    const int e0  = blockIdx.x * TE;

    if (tid < TE) {
        int s = src[e0 + tid];
        int d = dst[e0 + tid];
        sid[tid] = s;
        did[tid] = d;
        dtS[tid] = timestamps[e0 + tid] - last_update[s];
        atomicAdd(&counts[s], 1.0f);
        atomicAdd(&counts[d], 1.0f);
    }
    __syncthreads();

    for (int i = tid; i < TE * 128; i += 256) {
        int e = i >> 7;
        int c = (i & 127) * 4;
        float4 v;
        if (c < 128) {
            v = *reinterpret_cast<const float4*>(&memory[(size_t)sid[e] * 128 + c]);
        } else if (c < 256) {
            v = *reinterpret_cast<const float4*>(&memory[(size_t)did[e] * 128 + (c - 128)]);
        } else if (c < 384) {
            v = *reinterpret_cast<const float4*>(&edge_features[(size_t)(e0 + e) * 128 + (c - 256)]);
        } else if (c < 484) {
            float dt = dtS[e];
            int t = c - 384;
            v.x = __cosf(fmaf(dt, time_w[t + 0], time_b[t + 0]));
            v.y = __cosf(fmaf(dt, time_w[t + 1], time_b[t + 1]));
            v.z = __cosf(fmaf(dt, time_w[t + 2], time_b[t + 2]));
            v.w = __cosf(fmaf(dt, time_w[t + 3], time_b[t + 3]));
        } else {
            v.x = v.y = v.z = v.w = 0.0f;
        }
        short4 s4;
        s4.x = f2bf(v.x); s4.y = f2bf(v.y); s4.z = f2bf(v.z); s4.w = f2bf(v.w);
        *reinterpret_cast<short4*>(&X[e][c]) = s4;
    }
    __syncthreads();

    const int w    = tid >> 6;
    const int l    = tid & 63;
    const int lrow = l & 15;
    const int lkg  = l >> 4;
    const int et   = w & 1;
    const int nh   = w >> 1;

    f32x4 acc[4];
#pragma unroll
    for (int n = 0; n < 4; n++) acc[n] = (f32x4){0.f, 0.f, 0.f, 0.f};

#pragma unroll 4
    for (int s = 0; s < 16; ++s) {
        bf16x8 A = *reinterpret_cast<const bf16x8*>(&X[et * 16 + lrow][s * 32 + lkg * 8]);
#pragma unroll
        for (int ntl = 0; ntl < 4; ++ntl) {
            int t = nh * 4 + ntl;
            bf16x8 B = *reinterpret_cast<const bf16x8*>(&wfm[(size_t)(((t * 16 + s) * 64) + l) * 8]);
            acc[ntl] = __builtin_amdgcn_mfma_f32_16x16x32_bf16(A, B, acc[ntl], 0, 0, 0);
        }
    }

#pragma unroll
    for (int ntl = 0; ntl < 4; ++ntl) {
        int j = nh * 64 + ntl * 16 + lrow;
        float bias = msg_b[j];
#pragma unroll
        for (int r = 0; r < 4; ++r) {
            int el = et * 16 + lkg * 4 + r;
            float m = acc[ntl][r] + bias;
            atomicAdd(&sums[(size_t)sid[el] * 128 + j], m);
            atomicAdd(&sums[(size_t)did[el] * 128 + j], m);
        }
    }
}

__global__ __launch_bounds__(256, 3) void tgn_gru_mfma(
    const float* __restrict__ memory,
    const float* __restrict__ last_update,
    const float* __restrict__ timestamps,
    const float* __restrict__ b_ih,
    const float* __restrict__ b_hh,
    const short* __restrict__ wfrag,
    float* __restrict__ out)
{
    __shared__ short X[GNT][264];
    __shared__ float cntS[GNT];

    const int tid = threadIdx.x;
    const int n0 = blockIdx.x * GNT;
    const float* sums   = out;
    const float* counts = out + (size_t)N_NODES * 128;

    if (tid < GNT) cntS[tid] = counts[n0 + tid];
    __syncthreads();

    for (int i = tid; i < GNT * 32; i += 256) {
        int m = i >> 5;
        int c = (i & 31) * 4;
        float inv = 1.0f / fmaxf(cntS[m], 1.0f);
        float4 v = *reinterpret_cast<const float4*>(&sums[(size_t)(n0 + m) * 128 + c]);
        short4 a4;
        a4.x = f2bf(v.x * inv); a4.y = f2bf(v.y * inv);
        a4.z = f2bf(v.z * inv); a4.w = f2bf(v.w * inv);
        *reinterpret_cast<short4*>(&X[m][c]) = a4;
        float4 mv = *reinterpret_cast<const float4*>(&memory[(size_t)(n0 + m) * 128 + c]);
        short4 m4;
        m4.x = f2bf(mv.x); m4.y = f2bf(mv.y); m4.z = f2bf(mv.z); m4.w = f2bf(mv.w);
        *reinterpret_cast<short4*>(&X[m][128 + c]) = m4;
    }
    __syncthreads();

    const int w    = tid >> 6;
    const int l    = tid & 63;
    const int lrow = l & 15;
    const int lkg  = l >> 4;

    f32x4 acc[4][2][2];
#pragma unroll
    for (int q = 0; q < 4; q++)
#pragma unroll
        for (int jt = 0; jt < 2; jt++)
#pragma unroll
            for (int mt = 0; mt < 2; mt++)
                acc[q][jt][mt] = (f32x4){0.f, 0.f, 0.f, 0.f};

    for (int s = 0; s < 8; ++s) {
        bf16x8 A[2];
#pragma unroll
        for (int mt = 0; mt < 2; ++mt)
            A[mt] = *reinterpret_cast<const bf16x8*>(&X[mt * 16 + lrow][s * 32 + lkg * 8]);
#pragma unroll
        for (int q = 0; q < 4; ++q)
#pragma unroll
            for (int jt = 0; jt < 2; ++jt) {
                int t = q * 8 + w * 2 + jt;
                bf16x8 B = *reinterpret_cast<const bf16x8*>(&wfrag[(size_t)(((t * 8 + s) * 64) + l) * 8]);
#pragma unroll
                for (int mt = 0; mt < 2; ++mt)
                    acc[q][jt][mt] = __builtin_amdgcn_mfma_f32_16x16x32_bf16(
                        A[mt], B, acc[q][jt][mt], 0, 0, 0);
            }
    }

    const float ts0 = timestamps[0];
#pragma unroll
    for (int jt = 0; jt < 2; ++jt) {
        int j = w * 32 + jt * 16 + lrow;
        float br  = b_ih[j]       + b_hh[j];
        float bz  = b_ih[128 + j] + b_hh[128 + j];
        float bin = b_ih[256 + j];
        float bhn = b_hh[256 + j];
#pragma unroll
        for (int mt = 0; mt < 2; ++mt) {
#pragma unroll
            for (int r = 0; r < 4; ++r) {
                int mloc = mt * 16 + lkg * 4 + r;
                int node = n0 + mloc;
                float rg  = acc[0][jt][mt][r] + br;
                float zg  = acc[1][jt][mt][r] + bz;
                float ing = acc[2][jt][mt][r] + bin;
                float hng = acc[3][jt][mt][r] + bhn;
                float rr = fsigmoid(rg);
                float zz = fsigmoid(zg);
                float nn = ftanh(ing + rr * hng);
                float mv = memory[(size_t)node * 128 + j];
                float h  = (1.0f - zz) * nn + zz * mv;
                out[(size_t)node * 128 + j] = (cntS[mloc] > 0.0f) ? h : mv;
            }
        }
    }
    if (tid < GNT) {
        int node = n0 + tid;
        out[(size_t)N_NODES * 128 + node] = (cntS[tid] > 0.0f) ? ts0 : last_update[node];
    }
}

// ---------------------------------------------------------------------------
extern "C" void kernel_launch(void* const* d_in, const int* in_sizes, int n_in,
                              void* d_out, int out_size, void* d_ws, size_t ws_size,
                              hipStream_t stream) {
    const float* memory        = (const float*)d_in[0];
    const float* last_update   = (const float*)d_in[1];
    const float* timestamps    = (const float*)d_in[2];
    const float* edge_features = (const float*)d_in[3];
    const float* msg_W         = (const float*)d_in[4];
    const float* msg_b         = (const float*)d_in[5];
    const float* gru_W_ih      = (const float*)d_in[6];
    const float* gru_W_hh      = (const float*)d_in[7];
    const float* gru_b_ih      = (const float*)d_in[8];
    const float* gru_b_hh      = (const float*)d_in[9];
    const float* time_w        = (const float*)d_in[10];
    const float* time_b        = (const float*)d_in[11];
    const int*   src           = (const int*)d_in[12];
    const int*   dst           = (const int*)d_in[13];

    float* out = (float*)d_out;
    char* ws = (char*)d_ws;

    const size_t OFF_WGRU = 0;                                   // 256 KB
    const size_t OFF_WMSG = 262144;                              // 128 KB
    const size_t OFF_MSG  = 393216;                              // E*128 bf16
    const size_t SZ_MSG   = (size_t)E_EDGES * 128 * 2;           // 25.6 MB
    const size_t OFF_IDX  = OFF_MSG + SZ_MSG;                    // N*CAP u32
    const size_t SZ_IDX   = (size_t)N_NODES * CAP * 4;           // 9.6 MB
    const size_t OFF_CNT  = OFF_IDX + SZ_IDX;                    // N u32
    const size_t OFF_OVF  = OFF_CNT + (size_t)N_NODES * 4;
    const size_t WS_NEED  = OFF_OVF + 4 + (size_t)OVF_MAX * 8;

    short* wfrag_gru = (short*)(ws + OFF_WGRU);
    short* wfrag_msg = (short*)(ws + OFF_WMSG);
    const int TICKET_BLOCKS = (E_EDGES + 255) / 256;             // 391

    if (ws_size >= WS_NEED) {
        short* msgb = (short*)(ws + OFF_MSG);
        uint*  idxv = (uint*)(ws + OFF_IDX);
        uint*  cnt  = (uint*)(ws + OFF_CNT);
        uint*  ovf  = (uint*)(ws + OFF_OVF);

        // zero cnt + ovf counter (contiguous, ~800 KB)
        hipMemsetAsync(ws + OFF_CNT, 0, (size_t)N_NODES * 4 + 16, stream);

        tgn_setup<<<768 + TICKET_BLOCKS, 256, 0, stream>>>(
            gru_W_ih, gru_W_hh, wfrag_gru, msg_W, wfrag_msg,
            src, dst, idxv, cnt, ovf);

        tgn_msg_bf<<<E_EDGES / MTE, 128, 0, stream>>>(
            memory, last_update, timestamps, edge_features, msg_b,
            time_w, time_b, src, dst, wfrag_msg, msgb);

        tgn_gru_bf<<<N_NODES / GNT, 256, 0, stream>>>(
            memory, last_update, timestamps, gru_b_ih, gru_b_hh, wfrag_gru,
            msgb, idxv, cnt, ovf, out);
    } else {
        hipMemsetAsync(d_out, 0, (size_t)out_size * sizeof(float), stream);
        float* sums   = out;
        float* counts = out + (size_t)N_NODES * 128;

        tgn_setup<<<768, 256, 0, stream>>>(
            gru_W_ih, gru_W_hh, wfrag_gru, msg_W, wfrag_msg,
            src, dst, nullptr, nullptr, nullptr);

        tgn_msg_mfma<<<E_EDGES / TE, 256, 0, stream>>>(
            memory, last_update, timestamps, edge_features, msg_b,
            time_w, time_b, src, dst, wfrag_msg, sums, counts);

        tgn_gru_mfma<<<N_NODES / GNT, 256, 0, stream>>>(
            memory, last_update, timestamps, gru_b_ih, gru_b_hh, wfrag_gru, out);
    }
}

// Round 15
// 232.772 us; speedup vs baseline: 1.1964x; 1.0160x over previous
//
#include <hip/hip_runtime.h>
#include <math.h>

#define N_NODES 200000
#define E_EDGES 100000
#define TIME_DIM 100
#define RAW_DIM 484   // 128 + 128 + 128 + 100
#define CAP 12        // per-node direct slots
#define OVF_MAX 8192

typedef short  bf16x8 __attribute__((ext_vector_type(8)));
typedef float  f32x4  __attribute__((ext_vector_type(4)));
typedef unsigned int uint;

__device__ __forceinline__ short f2bf(float f) {
    unsigned u = __builtin_bit_cast(unsigned, f);
    u = (u + 0x7FFFu + ((u >> 16) & 1u)) >> 16;   // RNE
    return (short)u;
}
__device__ __forceinline__ float bf2f(unsigned short u) {
    return __builtin_bit_cast(float, ((unsigned)u) << 16);
}
__device__ __forceinline__ float fsigmoid(float x) {
    return __builtin_amdgcn_rcpf(1.0f + __expf(-x));
}
__device__ __forceinline__ float ftanh(float x) {
    float t = __expf(2.0f * x);
    return 1.0f - 2.0f * __builtin_amdgcn_rcpf(t + 1.0f);
}
__device__ __forceinline__ unsigned cvtpk(float a, float b) {
    unsigned r;
    asm("v_cvt_pk_bf16_f32 %0, %1, %2" : "=v"(r) : "v"(a), "v"(b));
    return r;
}
__device__ __forceinline__ bf16x8 pack8(float4 a, float4 b) {
    uint4 u = {cvtpk(a.x, a.y), cvtpk(a.z, a.w), cvtpk(b.x, b.y), cvtpk(b.z, b.w)};
    return __builtin_bit_cast(bf16x8, u);
}

// ---------------------------------------------------------------------------
// Setup: weight-fragment packs + ticket slot lists (STANDALONE — proven).
// ---------------------------------------------------------------------------
__global__ __launch_bounds__(256) void tgn_setup(
    const float* __restrict__ Wih, const float* __restrict__ Whh,
    short* __restrict__ wfg,
    const float* __restrict__ msgW, short* __restrict__ wfm,
    const int* __restrict__ src, const int* __restrict__ dst,
    uint* __restrict__ idxv, uint* __restrict__ cnt, uint* __restrict__ ovf)
{
    int b = blockIdx.x;
    int tid = threadIdx.x;
    if (b < 512) {
        int idx = b * 256 + tid;                 // 0 .. 131071
        int j = idx & 7;
        int l = (idx >> 3) & 63;
        int s = (idx >> 9) & 7;
        int t = idx >> 12;
        int n = t * 16 + (l & 15);
        int k = s * 32 + (l >> 4) * 8 + j;
        int half = k >> 7;
        int kk = k & 127;
        float v;
        if (n < 256) {
            v = half ? Whh[(size_t)n * 128 + kk] : Wih[(size_t)n * 128 + kk];
        } else if (n < 384) {
            v = half ? 0.0f : Wih[(size_t)n * 128 + kk];
        } else {
            v = half ? Whh[(size_t)(n - 128) * 128 + kk] : 0.0f;
        }
        wfg[idx] = f2bf(v);
    } else if (b < 768) {
        int idx = (b - 512) * 256 + tid;         // 0 .. 65535
        int j = idx & 7;
        int l = (idx >> 3) & 63;
        int s = (idx >> 9) & 15;
        int t = idx >> 13;
        int n = t * 16 + (l & 15);
        int k = s * 32 + (l >> 4) * 8 + j;
        float v = (k < RAW_DIM) ? msgW[(size_t)n * RAW_DIM + k] : 0.0f;
        wfm[idx] = f2bf(v);
    } else {
        int i = (b - 768) * 256 + tid;
        if (i < E_EDGES) {
            int s = src[i];
            int d = dst[i];
            uint rs = atomicAdd(&cnt[s], 1u);
            if (rs < (uint)CAP) {
                idxv[(size_t)s * CAP + rs] = (uint)i;
            } else {
                uint o = atomicAdd(&ovf[0], 1u);
                if (o < OVF_MAX) { ovf[1 + 2 * o] = (uint)s; ovf[2 + 2 * o] = (uint)i; }
            }
            uint rd = atomicAdd(&cnt[d], 1u);
            if (rd < (uint)CAP) {
                idxv[(size_t)d * CAP + rd] = (uint)i;
            } else {
                uint o = atomicAdd(&ovf[0], 1u);
                if (o < OVF_MAX) { ovf[1 + 2 * o] = (uint)d; ovf[2 + 2 * o] = (uint)i; }
            }
        }
    }
}

// ---------------------------------------------------------------------------
// Kernel A (bf16 store): register-gather MFMA message MLP, NO atomics.
// (verbatim round-14 passing kernel)
// ---------------------------------------------------------------------------
#define MTE 32

__global__ __launch_bounds__(128, 2) void tgn_msg_bf(
    const float* __restrict__ memory,
    const float* __restrict__ last_update,
    const float* __restrict__ timestamps,
    const float* __restrict__ edge_features,
    const float* __restrict__ msg_b,
    const float* __restrict__ time_w,
    const float* __restrict__ time_b,
    const int*   __restrict__ src,
    const int*   __restrict__ dst,
    const short* __restrict__ wfm,
    short* __restrict__ msgb)
{
    const int tid  = threadIdx.x;
    const int wv   = tid >> 6;
    const int l    = tid & 63;
    const int lrow = l & 15;
    const int lkg  = l >> 4;
    const int e0   = blockIdx.x * MTE + wv * 16;
    const int e    = e0 + lrow;

    const int sid = src[e];
    const int did = dst[e];
    const float dt = timestamps[e] - last_update[sid];

    const float* srcm = memory        + (size_t)sid * 128 + lkg * 8;
    const float* dstm = memory        + (size_t)did * 128 + lkg * 8;
    const float* ef   = edge_features + (size_t)e   * 128 + lkg * 8;
    float4 bufS[8], bufD[8], bufE[8];
#pragma unroll
    for (int s = 0; s < 4; ++s) {
        bufS[2 * s]     = *reinterpret_cast<const float4*>(srcm + s * 32);
        bufS[2 * s + 1] = *reinterpret_cast<const float4*>(srcm + s * 32 + 4);
        bufD[2 * s]     = *reinterpret_cast<const float4*>(dstm + s * 32);
        bufD[2 * s + 1] = *reinterpret_cast<const float4*>(dstm + s * 32 + 4);
        bufE[2 * s]     = *reinterpret_cast<const float4*>(ef + s * 32);
        bufE[2 * s + 1] = *reinterpret_cast<const float4*>(ef + s * 32 + 4);
    }

    bf16x8 afr[16];
#pragma unroll
    for (int s = 12; s < 16; ++s) {
        int k0 = s * 32 + lkg * 8;
        float4 lo, hi;
#pragma unroll
        for (int j = 0; j < 8; ++j) {
            int k = k0 + j;
            float v = 0.0f;
            if (k < RAW_DIM) {
                int t = k - 384;
                v = __cosf(fmaf(dt, time_w[t], time_b[t]));
            }
            if (j < 4) (&lo.x)[j] = v; else (&hi.x)[j - 4] = v;
        }
        afr[s] = pack8(lo, hi);
    }

#pragma unroll
    for (int s = 0; s < 4; ++s) {
        afr[s]     = pack8(bufS[2 * s], bufS[2 * s + 1]);
        afr[4 + s] = pack8(bufD[2 * s], bufD[2 * s + 1]);
        afr[8 + s] = pack8(bufE[2 * s], bufE[2 * s + 1]);
    }

    f32x4 acc[8];
#pragma unroll
    for (int t = 0; t < 8; ++t) acc[t] = (f32x4){0.f, 0.f, 0.f, 0.f};

#pragma unroll
    for (int s = 0; s < 16; ++s) {
#pragma unroll
        for (int t = 0; t < 8; ++t) {
            bf16x8 B = *reinterpret_cast<const bf16x8*>(
                &wfm[(size_t)(((t * 16 + s) * 64) + l) * 8]);
            acc[t] = __builtin_amdgcn_mfma_f32_16x16x32_bf16(afr[s], B, acc[t], 0, 0, 0);
        }
    }

    const bool even = (l & 1) == 0;
#pragma unroll
    for (int r = 0; r < 4; ++r) {
        int erow = e0 + lkg * 4 + r;
#pragma unroll
        for (int t = 0; t < 8; ++t) {
            int j = t * 16 + lrow;
            float m = acc[t][r] + msg_b[j];
            float mo = __shfl_xor(m, 1);
            if (even) {
                unsigned pk = cvtpk(m, mo);
                *reinterpret_cast<unsigned*>(&msgb[(size_t)erow * 128 + j]) = pk;
            }
        }
    }
}

// ---------------------------------------------------------------------------
// Kernel B: 512-thread / 8-wave GRU.  Each wave owns a 16-wide j-slice ->
// acc = [4 quadrants][2 mt] f32x4 = 32 AGPR (half of r14) -> higher occupancy.
// Gather: 16 threads/node x 8 dims.  Same proven fragment/index maps.
// ---------------------------------------------------------------------------
#define GNT 32

__global__ __launch_bounds__(512, 6) void tgn_gru_bf8(
    const float* __restrict__ memory,
    const float* __restrict__ last_update,
    const float* __restrict__ timestamps,
    const float* __restrict__ b_ih,
    const float* __restrict__ b_hh,
    const short* __restrict__ wfrag,
    const short* __restrict__ msgb,
    const uint*  __restrict__ idxv,
    const uint*  __restrict__ cnt,
    const uint*  __restrict__ ovf,
    float* __restrict__ out)
{
    __shared__ short X[GNT][264];
    __shared__ float cntS[GNT];

    const int tid = threadIdx.x;
    const int n0 = blockIdx.x * GNT;

    const int nloc = tid >> 4;     // 0..31
    const int p    = tid & 15;     // dims [p*8, p*8+8)
    const int node = n0 + nloc;

    const uint c = cnt[node];
    if (p == 0) cntS[nloc] = (float)c;

    // stage memory -> X[:, 128:256]: 1024 4-elem chunks over 512 threads
#pragma unroll
    for (int it = 0; it < 2; ++it) {
        int i = tid + it * 512;
        int m = i >> 5;
        int c4 = (i & 31) * 4;
        float4 mv = *reinterpret_cast<const float4*>(&memory[(size_t)(n0 + m) * 128 + c4]);
        uint2 u = {cvtpk(mv.x, mv.y), cvtpk(mv.z, mv.w)};
        *reinterpret_cast<uint2*>(&X[m][128 + c4]) = u;
    }

    // gather-aggregate agg -> X[:, 0:128]; 16 threads/node, 8 dims each
    {
        float a[8];
#pragma unroll
        for (int q = 0; q < 8; ++q) a[q] = 0.0f;
        const uint cm = (c < (uint)CAP) ? c : (uint)CAP;
        if (cm > 0u) {
            const uint* ip = idxv + (size_t)node * CAP;
            uint4 i0 = *reinterpret_cast<const uint4*>(ip);
            uint4 i1 = {0, 0, 0, 0}, i2 = {0, 0, 0, 0};
            if (cm > 4u) i1 = *reinterpret_cast<const uint4*>(ip + 4);
            if (cm > 8u) i2 = *reinterpret_cast<const uint4*>(ip + 8);
            uint idxs[12];
            idxs[0] = i0.x; idxs[1] = i0.y; idxs[2]  = i0.z; idxs[3]  = i0.w;
            idxs[4] = i1.x; idxs[5] = i1.y; idxs[6]  = i1.z; idxs[7]  = i1.w;
            idxs[8] = i2.x; idxs[9] = i2.y; idxs[10] = i2.z; idxs[11] = i2.w;
#pragma unroll
            for (int i = 0; i < 12; ++i) {
                if ((uint)i < cm) {
                    const short* row = msgb + (size_t)idxs[i] * 128 + p * 8;
                    bf16x8 v0 = *reinterpret_cast<const bf16x8*>(row);
#pragma unroll
                    for (int q = 0; q < 8; ++q) a[q] += bf2f((unsigned short)v0[q]);
                }
            }
        }
        if (c > (uint)CAP) {                   // rare: scan overflow list
            uint L = ovf[0];
            if (L > OVF_MAX) L = OVF_MAX;
            for (uint i = 0; i < L; ++i) {
                if (ovf[1 + 2 * i] == (uint)node) {
                    uint eid = ovf[2 + 2 * i];
                    const short* row = msgb + (size_t)eid * 128 + p * 8;
                    bf16x8 v0 = *reinterpret_cast<const bf16x8*>(row);
#pragma unroll
                    for (int q = 0; q < 8; ++q) a[q] += bf2f((unsigned short)v0[q]);
                }
            }
        }
        float inv = (c > 0u) ? (1.0f / (float)c) : 0.0f;
#pragma unroll
        for (int q = 0; q < 8; ++q) a[q] *= inv;
        float4 A0 = {a[0], a[1], a[2], a[3]};
        float4 A1 = {a[4], a[5], a[6], a[7]};
        *reinterpret_cast<bf16x8*>(&X[nloc][p * 8]) = pack8(A0, A1);
    }
    __syncthreads();

    const int w    = tid >> 6;     // wave 0..7 -> j-slice [w*16, w*16+16)
    const int l    = tid & 63;
    const int lrow = l & 15;
    const int lkg  = l >> 4;

    f32x4 acc[4][2];   // [quadrant][mt]
#pragma unroll
    for (int q = 0; q < 4; q++)
#pragma unroll
        for (int mt = 0; mt < 2; mt++)
            acc[q][mt] = (f32x4){0.f, 0.f, 0.f, 0.f};

    for (int s = 0; s < 8; ++s) {
        bf16x8 A[2];
#pragma unroll
        for (int mt = 0; mt < 2; ++mt)
            A[mt] = *reinterpret_cast<const bf16x8*>(&X[mt * 16 + lrow][s * 32 + lkg * 8]);
#pragma unroll
        for (int q = 0; q < 4; ++q) {
            int t = q * 8 + w;
            bf16x8 B = *reinterpret_cast<const bf16x8*>(&wfrag[(size_t)(((t * 8 + s) * 64) + l) * 8]);
#pragma unroll
            for (int mt = 0; mt < 2; ++mt)
                acc[q][mt] = __builtin_amdgcn_mfma_f32_16x16x32_bf16(
                    A[mt], B, acc[q][mt], 0, 0, 0);
        }
    }

    const float ts0 = timestamps[0];

    {
        int j = w * 16 + lrow;
        float br  = b_ih[j]       + b_hh[j];
        float bz  = b_ih[128 + j] + b_hh[128 + j];
        float bin = b_ih[256 + j];
        float bhn = b_hh[256 + j];
#pragma unroll
        for (int mt = 0; mt < 2; ++mt) {
#pragma unroll
            for (int r = 0; r < 4; ++r) {
                int mloc = mt * 16 + lkg * 4 + r;
                int nodew = n0 + mloc;
                float rg  = acc[0][mt][r] + br;
                float zg  = acc[1][mt][r] + bz;
                float ing = acc[2][mt][r] + bin;
                float hng = acc[3][mt][r] + bhn;
                float rr = fsigmoid(rg);
                float zz = fsigmoid(zg);
                float nn = ftanh(ing + rr * hng);
                float mv = bf2f((unsigned short)X[mloc][128 + j]);
                float h  = (1.0f - zz) * nn + zz * mv;
                out[(size_t)nodew * 128 + j] = (cntS[mloc] > 0.0f) ? h : mv;
            }
        }
    }

    if (tid < GNT) {
        int noded = n0 + tid;
        out[(size_t)N_NODES * 128 + noded] = (cntS[tid] > 0.0f) ? ts0 : last_update[noded];
    }
}

// ---------------------------------------------------------------------------
// Fallback (round-7 proven): f32 atomics via d_out.
// ---------------------------------------------------------------------------
#define TE 32

__global__ __launch_bounds__(256, 2) void tgn_msg_mfma(
    const float* __restrict__ memory,
    const float* __restrict__ last_update,
    const float* __restrict__ timestamps,
    const float* __restrict__ edge_features,
    const float* __restrict__ msg_b,
    const float* __restrict__ time_w,
    const float* __restrict__ time_b,
    const int*   __restrict__ src,
    const int*   __restrict__ dst,
    const short* __restrict__ wfm,
    float* __restrict__ sums,
    float* __restrict__ counts)
{
    __shared__ short X[TE][520];
    __shared__ int   sid[TE];
    __shared__ int   did[TE];
    __shared__ float dtS[TE];

    const int tid = threadIdx.x;
    const int e0  = blockIdx.x * TE;

    if (tid < TE) {
        int s = src[e0 + tid];
        int d = dst[e0 + tid];
        sid[tid] = s;
        did[tid] = d;
        dtS[tid] = timestamps[e0 + tid] - last_update[s];
        atomicAdd(&counts[s], 1.0f);
        atomicAdd(&counts[d], 1.0f);
    }
    __syncthreads();

    for (int i = tid; i < TE * 128; i += 256) {
        int e = i >> 7;
        int c = (i & 127) * 4;
        float4 v;
        if (c < 128) {
            v = *reinterpret_cast<const float4*>(&memory[(size_t)sid[e] * 128 + c]);
        } else if (c < 256) {
            v = *reinterpret_cast<const float4*>(&memory[(size_t)did[e] * 128 + (c - 128)]);
        } else if (c < 384) {
            v = *reinterpret_cast<const float4*>(&edge_features[(size_t)(e0 + e) * 128 + (c - 256)]);
        } else if (c < 484) {
            float dt = dtS[e];
            int t = c - 384;
            v.x = __cosf(fmaf(dt, time_w[t + 0], time_b[t + 0]));
            v.y = __cosf(fmaf(dt, time_w[t + 1], time_b[t + 1]));
            v.z = __cosf(fmaf(dt, time_w[t + 2], time_b[t + 2]));
            v.w = __cosf(fmaf(dt, time_w[t + 3], time_b[t + 3]));
        } else {
            v.x = v.y = v.z = v.w = 0.0f;
        }
        short4 s4;
        s4.x = f2bf(v.x); s4.y = f2bf(v.y); s4.z = f2bf(v.z); s4.w = f2bf(v.w);
        *reinterpret_cast<short4*>(&X[e][c]) = s4;
    }
    __syncthreads();

    const int w    = tid >> 6;
    const int l    = tid & 63;
    const int lrow = l & 15;
    const int lkg  = l >> 4;
    const int et   = w & 1;
    const int nh   = w >> 1;

    f32x4 acc[4];
#pragma unroll
    for (int n = 0; n < 4; n++) acc[n] = (f32x4){0.f, 0.f, 0.f, 0.f};

#pragma unroll 4
    for (int s = 0; s < 16; ++s) {
        bf16x8 A = *reinterpret_cast<const bf16x8*>(&X[et * 16 + lrow][s * 32 + lkg * 8]);
#pragma unroll
        for (int ntl = 0; ntl < 4; ++ntl) {
            int t = nh * 4 + ntl;
            bf16x8 B = *reinterpret_cast<const bf16x8*>(&wfm[(size_t)(((t * 16 + s) * 64) + l) * 8]);
            acc[ntl] = __builtin_amdgcn_mfma_f32_16x16x32_bf16(A, B, acc[ntl], 0, 0, 0);
        }
    }

#pragma unroll
    for (int ntl = 0; ntl < 4; ++ntl) {
        int j = nh * 64 + ntl * 16 + lrow;
        float bias = msg_b[j];
#pragma unroll
        for (int r = 0; r < 4; ++r) {
            int el = et * 16 + lkg * 4 + r;
            float m = acc[ntl][r] + bias;
            atomicAdd(&sums[(size_t)sid[el] * 128 + j], m);
            atomicAdd(&sums[(size_t)did[el] * 128 + j], m);
        }
    }
}

__global__ __launch_bounds__(256, 3) void tgn_gru_mfma(
    const float* __restrict__ memory,
    const float* __restrict__ last_update,
    const float* __restrict__ timestamps,
    const float* __restrict__ b_ih,
    const float* __restrict__ b_hh,
    const short* __restrict__ wfrag,
    float* __restrict__ out)
{
    __shared__ short X[GNT][264];
    __shared__ float cntS[GNT];

    const int tid = threadIdx.x;
    const int n0 = blockIdx.x * GNT;
    const float* sums   = out;
    const float* counts = out + (size_t)N_NODES * 128;

    if (tid < GNT) cntS[tid] = counts[n0 + tid];
    __syncthreads();

    for (int i = tid; i < GNT * 32; i += 256) {
        int m = i >> 5;
        int c = (i & 31) * 4;
        float inv = 1.0f / fmaxf(cntS[m], 1.0f);
        float4 v = *reinterpret_cast<const float4*>(&sums[(size_t)(n0 + m) * 128 + c]);
        short4 a4;
        a4.x = f2bf(v.x * inv); a4.y = f2bf(v.y * inv);
        a4.z = f2bf(v.z * inv); a4.w = f2bf(v.w * inv);
        *reinterpret_cast<short4*>(&X[m][c]) = a4;
        float4 mv = *reinterpret_cast<const float4*>(&memory[(size_t)(n0 + m) * 128 + c]);
        short4 m4;
        m4.x = f2bf(mv.x); m4.y = f2bf(mv.y); m4.z = f2bf(mv.z); m4.w = f2bf(mv.w);
        *reinterpret_cast<short4*>(&X[m][128 + c]) = m4;
    }
    __syncthreads();

    const int w    = tid >> 6;
    const int l    = tid & 63;
    const int lrow = l & 15;
    const int lkg  = l >> 4;

    f32x4 acc[4][2][2];
#pragma unroll
    for (int q = 0; q < 4; q++)
#pragma unroll
        for (int jt = 0; jt < 2; jt++)
#pragma unroll
            for (int mt = 0; mt < 2; mt++)
                acc[q][jt][mt] = (f32x4){0.f, 0.f, 0.f, 0.f};

    for (int s = 0; s < 8; ++s) {
        bf16x8 A[2];
#pragma unroll
        for (int mt = 0; mt < 2; ++mt)
            A[mt] = *reinterpret_cast<const bf16x8*>(&X[mt * 16 + lrow][s * 32 + lkg * 8]);
#pragma unroll
        for (int q = 0; q < 4; ++q)
#pragma unroll
            for (int jt = 0; jt < 2; ++jt) {
                int t = q * 8 + w * 2 + jt;
                bf16x8 B = *reinterpret_cast<const bf16x8*>(&wfrag[(size_t)(((t * 8 + s) * 64) + l) * 8]);
#pragma unroll
                for (int mt = 0; mt < 2; ++mt)
                    acc[q][jt][mt] = __builtin_amdgcn_mfma_f32_16x16x32_bf16(
                        A[mt], B, acc[q][jt][mt], 0, 0, 0);
            }
    }

    const float ts0 = timestamps[0];
#pragma unroll
    for (int jt = 0; jt < 2; ++jt) {
        int j = w * 32 + jt * 16 + lrow;
        float br  = b_ih[j]       + b_hh[j];
        float bz  = b_ih[128 + j] + b_hh[128 + j];
        float bin = b_ih[256 + j];
        float bhn = b_hh[256 + j];
#pragma unroll
        for (int mt = 0; mt < 2; ++mt) {
#pragma unroll
            for (int r = 0; r < 4; ++r) {
                int mloc = mt * 16 + lkg * 4 + r;
                int node = n0 + mloc;
                float rg  = acc[0][jt][mt][r] + br;
                float zg  = acc[1][jt][mt][r] + bz;
                float ing = acc[2][jt][mt][r] + bin;
                float hng = acc[3][jt][mt][r] + bhn;
                float rr = fsigmoid(rg);
                float zz = fsigmoid(zg);
                float nn = ftanh(ing + rr * hng);
                float mv = memory[(size_t)node * 128 + j];
                float h  = (1.0f - zz) * nn + zz * mv;
                out[(size_t)node * 128 + j] = (cntS[mloc] > 0.0f) ? h : mv;
            }
        }
    }
    if (tid < GNT) {
        int node = n0 + tid;
        out[(size_t)N_NODES * 128 + node] = (cntS[tid] > 0.0f) ? ts0 : last_update[node];
    }
}

// ---------------------------------------------------------------------------
extern "C" void kernel_launch(void* const* d_in, const int* in_sizes, int n_in,
                              void* d_out, int out_size, void* d_ws, size_t ws_size,
                              hipStream_t stream) {
    const float* memory        = (const float*)d_in[0];
    const float* last_update   = (const float*)d_in[1];
    const float* timestamps    = (const float*)d_in[2];
    const float* edge_features = (const float*)d_in[3];
    const float* msg_W         = (const float*)d_in[4];
    const float* msg_b         = (const float*)d_in[5];
    const float* gru_W_ih      = (const float*)d_in[6];
    const float* gru_W_hh      = (const float*)d_in[7];
    const float* gru_b_ih      = (const float*)d_in[8];
    const float* gru_b_hh      = (const float*)d_in[9];
    const float* time_w        = (const float*)d_in[10];
    const float* time_b        = (const float*)d_in[11];
    const int*   src           = (const int*)d_in[12];
    const int*   dst           = (const int*)d_in[13];

    float* out = (float*)d_out;
    char* ws = (char*)d_ws;

    const size_t OFF_WGRU = 0;                                   // 256 KB
    const size_t OFF_WMSG = 262144;                              // 128 KB
    const size_t OFF_MSG  = 393216;                              // E*128 bf16
    const size_t SZ_MSG   = (size_t)E_EDGES * 128 * 2;           // 25.6 MB
    const size_t OFF_IDX  = OFF_MSG + SZ_MSG;                    // N*CAP u32
    const size_t SZ_IDX   = (size_t)N_NODES * CAP * 4;           // 9.6 MB
    const size_t OFF_CNT  = OFF_IDX + SZ_IDX;                    // N u32
    const size_t OFF_OVF  = OFF_CNT + (size_t)N_NODES * 4;
    const size_t WS_NEED  = OFF_OVF + 4 + (size_t)OVF_MAX * 8;

    short* wfrag_gru = (short*)(ws + OFF_WGRU);
    short* wfrag_msg = (short*)(ws + OFF_WMSG);
    const int TICKET_BLOCKS = (E_EDGES + 255) / 256;             // 391

    if (ws_size >= WS_NEED) {
        short* msgb = (short*)(ws + OFF_MSG);
        uint*  idxv = (uint*)(ws + OFF_IDX);
        uint*  cnt  = (uint*)(ws + OFF_CNT);
        uint*  ovf  = (uint*)(ws + OFF_OVF);

        hipMemsetAsync(ws + OFF_CNT, 0, (size_t)N_NODES * 4 + 16, stream);

        tgn_setup<<<768 + TICKET_BLOCKS, 256, 0, stream>>>(
            gru_W_ih, gru_W_hh, wfrag_gru, msg_W, wfrag_msg,
            src, dst, idxv, cnt, ovf);

        tgn_msg_bf<<<E_EDGES / MTE, 128, 0, stream>>>(
            memory, last_update, timestamps, edge_features, msg_b,
            time_w, time_b, src, dst, wfrag_msg, msgb);

        tgn_gru_bf8<<<N_NODES / GNT, 512, 0, stream>>>(
            memory, last_update, timestamps, gru_b_ih, gru_b_hh, wfrag_gru,
            msgb, idxv, cnt, ovf, out);
    } else {
        hipMemsetAsync(d_out, 0, (size_t)out_size * sizeof(float), stream);
        float* sums   = out;
        float* counts = out + (size_t)N_NODES * 128;

        tgn_setup<<<768, 256, 0, stream>>>(
            gru_W_ih, gru_W_hh, wfrag_gru, msg_W, wfrag_msg,
            src, dst, nullptr, nullptr, nullptr);

        tgn_msg_mfma<<<E_EDGES / TE, 256, 0, stream>>>(
            memory, last_update, timestamps, edge_features, msg_b,
            time_w, time_b, src, dst, wfrag_msg, sums, counts);

        tgn_gru_mfma<<<N_NODES / GNT, 256, 0, stream>>>(
            memory, last_update, timestamps, gru_b_ih, gru_b_hh, wfrag_gru, out);
    }
}

// Round 16
// 229.431 us; speedup vs baseline: 1.2138x; 1.0146x over previous
//
#include <hip/hip_runtime.h>
#include <math.h>

#define N_NODES 200000
#define E_EDGES 100000
#define TIME_DIM 100
#define RAW_DIM 484   // 128 + 128 + 128 + 100
#define CAP 12        // per-node direct slots
#define OVF_MAX 8192

typedef short  bf16x8 __attribute__((ext_vector_type(8)));
typedef float  f32x4  __attribute__((ext_vector_type(4)));
typedef unsigned int uint;

__device__ __forceinline__ short f2bf(float f) {
    unsigned u = __builtin_bit_cast(unsigned, f);
    u = (u + 0x7FFFu + ((u >> 16) & 1u)) >> 16;   // RNE
    return (short)u;
}
__device__ __forceinline__ float bf2f(unsigned short u) {
    return __builtin_bit_cast(float, ((unsigned)u) << 16);
}
__device__ __forceinline__ float fsigmoid(float x) {
    return __builtin_amdgcn_rcpf(1.0f + __expf(-x));
}
__device__ __forceinline__ float ftanh(float x) {
    float t = __expf(2.0f * x);
    return 1.0f - 2.0f * __builtin_amdgcn_rcpf(t + 1.0f);
}
__device__ __forceinline__ unsigned cvtpk(float a, float b) {
    unsigned r;
    asm("v_cvt_pk_bf16_f32 %0, %1, %2" : "=v"(r) : "v"(a), "v"(b));
    return r;
}
__device__ __forceinline__ bf16x8 pack8(float4 a, float4 b) {
    uint4 u = {cvtpk(a.x, a.y), cvtpk(a.z, a.w), cvtpk(b.x, b.y), cvtpk(b.z, b.w)};
    return __builtin_bit_cast(bf16x8, u);
}

// ---------------------------------------------------------------------------
// Setup: weight-fragment packs + ticket slot lists (STANDALONE — proven).
// ---------------------------------------------------------------------------
__global__ __launch_bounds__(256) void tgn_setup(
    const float* __restrict__ Wih, const float* __restrict__ Whh,
    short* __restrict__ wfg,
    const float* __restrict__ msgW, short* __restrict__ wfm,
    const int* __restrict__ src, const int* __restrict__ dst,
    uint* __restrict__ idxv, uint* __restrict__ cnt, uint* __restrict__ ovf)
{
    int b = blockIdx.x;
    int tid = threadIdx.x;
    if (b < 512) {
        int idx = b * 256 + tid;                 // 0 .. 131071
        int j = idx & 7;
        int l = (idx >> 3) & 63;
        int s = (idx >> 9) & 7;
        int t = idx >> 12;
        int n = t * 16 + (l & 15);
        int k = s * 32 + (l >> 4) * 8 + j;
        int half = k >> 7;
        int kk = k & 127;
        float v;
        if (n < 256) {
            v = half ? Whh[(size_t)n * 128 + kk] : Wih[(size_t)n * 128 + kk];
        } else if (n < 384) {
            v = half ? 0.0f : Wih[(size_t)n * 128 + kk];
        } else {
            v = half ? Whh[(size_t)(n - 128) * 128 + kk] : 0.0f;
        }
        wfg[idx] = f2bf(v);
    } else if (b < 768) {
        int idx = (b - 512) * 256 + tid;         // 0 .. 65535
        int j = idx & 7;
        int l = (idx >> 3) & 63;
        int s = (idx >> 9) & 15;
        int t = idx >> 13;
        int n = t * 16 + (l & 15);
        int k = s * 32 + (l >> 4) * 8 + j;
        float v = (k < RAW_DIM) ? msgW[(size_t)n * RAW_DIM + k] : 0.0f;
        wfm[idx] = f2bf(v);
    } else {
        int i = (b - 768) * 256 + tid;
        if (i < E_EDGES) {
            int s = src[i];
            int d = dst[i];
            uint rs = atomicAdd(&cnt[s], 1u);
            if (rs < (uint)CAP) {
                idxv[(size_t)s * CAP + rs] = (uint)i;
            } else {
                uint o = atomicAdd(&ovf[0], 1u);
                if (o < OVF_MAX) { ovf[1 + 2 * o] = (uint)s; ovf[2 + 2 * o] = (uint)i; }
            }
            uint rd = atomicAdd(&cnt[d], 1u);
            if (rd < (uint)CAP) {
                idxv[(size_t)d * CAP + rd] = (uint)i;
            } else {
                uint o = atomicAdd(&ovf[0], 1u);
                if (o < OVF_MAX) { ovf[1 + 2 * o] = (uint)d; ovf[2 + 2 * o] = (uint)i; }
            }
        }
    }
}

// ---------------------------------------------------------------------------
// Kernel A (bf16 store): register-gather MFMA message MLP, NO atomics.
// (verbatim round-14/15 passing kernel)
// ---------------------------------------------------------------------------
#define MTE 32

__global__ __launch_bounds__(128, 2) void tgn_msg_bf(
    const float* __restrict__ memory,
    const float* __restrict__ last_update,
    const float* __restrict__ timestamps,
    const float* __restrict__ edge_features,
    const float* __restrict__ msg_b,
    const float* __restrict__ time_w,
    const float* __restrict__ time_b,
    const int*   __restrict__ src,
    const int*   __restrict__ dst,
    const short* __restrict__ wfm,
    short* __restrict__ msgb)
{
    const int tid  = threadIdx.x;
    const int wv   = tid >> 6;
    const int l    = tid & 63;
    const int lrow = l & 15;
    const int lkg  = l >> 4;
    const int e0   = blockIdx.x * MTE + wv * 16;
    const int e    = e0 + lrow;

    const int sid = src[e];
    const int did = dst[e];
    const float dt = timestamps[e] - last_update[sid];

    const float* srcm = memory        + (size_t)sid * 128 + lkg * 8;
    const float* dstm = memory        + (size_t)did * 128 + lkg * 8;
    const float* ef   = edge_features + (size_t)e   * 128 + lkg * 8;
    float4 bufS[8], bufD[8], bufE[8];
#pragma unroll
    for (int s = 0; s < 4; ++s) {
        bufS[2 * s]     = *reinterpret_cast<const float4*>(srcm + s * 32);
        bufS[2 * s + 1] = *reinterpret_cast<const float4*>(srcm + s * 32 + 4);
        bufD[2 * s]     = *reinterpret_cast<const float4*>(dstm + s * 32);
        bufD[2 * s + 1] = *reinterpret_cast<const float4*>(dstm + s * 32 + 4);
        bufE[2 * s]     = *reinterpret_cast<const float4*>(ef + s * 32);
        bufE[2 * s + 1] = *reinterpret_cast<const float4*>(ef + s * 32 + 4);
    }

    bf16x8 afr[16];
#pragma unroll
    for (int s = 12; s < 16; ++s) {
        int k0 = s * 32 + lkg * 8;
        float4 lo, hi;
#pragma unroll
        for (int j = 0; j < 8; ++j) {
            int k = k0 + j;
            float v = 0.0f;
            if (k < RAW_DIM) {
                int t = k - 384;
                v = __cosf(fmaf(dt, time_w[t], time_b[t]));
            }
            if (j < 4) (&lo.x)[j] = v; else (&hi.x)[j - 4] = v;
        }
        afr[s] = pack8(lo, hi);
    }

#pragma unroll
    for (int s = 0; s < 4; ++s) {
        afr[s]     = pack8(bufS[2 * s], bufS[2 * s + 1]);
        afr[4 + s] = pack8(bufD[2 * s], bufD[2 * s + 1]);
        afr[8 + s] = pack8(bufE[2 * s], bufE[2 * s + 1]);
    }

    f32x4 acc[8];
#pragma unroll
    for (int t = 0; t < 8; ++t) acc[t] = (f32x4){0.f, 0.f, 0.f, 0.f};

#pragma unroll
    for (int s = 0; s < 16; ++s) {
#pragma unroll
        for (int t = 0; t < 8; ++t) {
            bf16x8 B = *reinterpret_cast<const bf16x8*>(
                &wfm[(size_t)(((t * 16 + s) * 64) + l) * 8]);
            acc[t] = __builtin_amdgcn_mfma_f32_16x16x32_bf16(afr[s], B, acc[t], 0, 0, 0);
        }
    }

    const bool even = (l & 1) == 0;
#pragma unroll
    for (int r = 0; r < 4; ++r) {
        int erow = e0 + lkg * 4 + r;
#pragma unroll
        for (int t = 0; t < 8; ++t) {
            int j = t * 16 + lrow;
            float m = acc[t][r] + msg_b[j];
            float mo = __shfl_xor(m, 1);
            if (even) {
                unsigned pk = cvtpk(m, mo);
                *reinterpret_cast<unsigned*>(&msgb[(size_t)erow * 128 + j]) = pk;
            }
        }
    }
}

// ---------------------------------------------------------------------------
// Kernel B: 64-node / 512-thread / 8-wave GRU.  Wave w owns a 16-wide
// j-slice; mt loops over 4 node-tiles -> acc [4][4] f32x4 = 64 AGPR.
// Halves per-node wfrag L2 traffic vs 32-node blocks.
// Gather: 8 threads/node x 16 dims (r14-proven code).
// ---------------------------------------------------------------------------
#define GNT 64

__global__ __launch_bounds__(512, 4) void tgn_gru_bf64(
    const float* __restrict__ memory,
    const float* __restrict__ last_update,
    const float* __restrict__ timestamps,
    const float* __restrict__ b_ih,
    const float* __restrict__ b_hh,
    const short* __restrict__ wfrag,
    const short* __restrict__ msgb,
    const uint*  __restrict__ idxv,
    const uint*  __restrict__ cnt,
    const uint*  __restrict__ ovf,
    float* __restrict__ out)
{
    __shared__ short X[GNT][264];
    __shared__ float cntS[GNT];

    const int tid = threadIdx.x;
    const int n0 = blockIdx.x * GNT;

    const int nloc = tid >> 3;     // 0..63
    const int p    = tid & 7;      // dims [p*16, p*16+16)
    const int node = n0 + nloc;

    const uint c = cnt[node];
    if (p == 0) cntS[nloc] = (float)c;

    // stage memory -> X[:, 128:256]: 64 nodes x 32 chunks = 2048 over 512 thr
#pragma unroll
    for (int it = 0; it < 4; ++it) {
        int i = tid + it * 512;
        int m = i >> 5;
        int c4 = (i & 31) * 4;
        float4 mv = *reinterpret_cast<const float4*>(&memory[(size_t)(n0 + m) * 128 + c4]);
        uint2 u = {cvtpk(mv.x, mv.y), cvtpk(mv.z, mv.w)};
        *reinterpret_cast<uint2*>(&X[m][128 + c4]) = u;
    }

    // gather-aggregate agg -> X[:, 0:128]; 8 threads/node, 16 dims each
    {
        float a[16];
#pragma unroll
        for (int q = 0; q < 16; ++q) a[q] = 0.0f;
        const uint cm = (c < (uint)CAP) ? c : (uint)CAP;
        if (cm > 0u) {
            const uint* ip = idxv + (size_t)node * CAP;
            uint4 i0 = *reinterpret_cast<const uint4*>(ip);
            uint4 i1 = {0, 0, 0, 0}, i2 = {0, 0, 0, 0};
            if (cm > 4u) i1 = *reinterpret_cast<const uint4*>(ip + 4);
            if (cm > 8u) i2 = *reinterpret_cast<const uint4*>(ip + 8);
            uint idxs[12];
            idxs[0] = i0.x; idxs[1] = i0.y; idxs[2]  = i0.z; idxs[3]  = i0.w;
            idxs[4] = i1.x; idxs[5] = i1.y; idxs[6]  = i1.z; idxs[7]  = i1.w;
            idxs[8] = i2.x; idxs[9] = i2.y; idxs[10] = i2.z; idxs[11] = i2.w;
#pragma unroll
            for (int i = 0; i < 12; ++i) {
                if ((uint)i < cm) {
                    const short* row = msgb + (size_t)idxs[i] * 128 + p * 16;
                    bf16x8 v0 = *reinterpret_cast<const bf16x8*>(row);
                    bf16x8 v1 = *reinterpret_cast<const bf16x8*>(row + 8);
#pragma unroll
                    for (int q = 0; q < 8; ++q) {
                        a[q]     += bf2f((unsigned short)v0[q]);
                        a[8 + q] += bf2f((unsigned short)v1[q]);
                    }
                }
            }
        }
        if (c > (uint)CAP) {                   // rare: scan overflow list
            uint L = ovf[0];
            if (L > OVF_MAX) L = OVF_MAX;
            for (uint i = 0; i < L; ++i) {
                if (ovf[1 + 2 * i] == (uint)node) {
                    uint eid = ovf[2 + 2 * i];
                    const short* row = msgb + (size_t)eid * 128 + p * 16;
                    bf16x8 v0 = *reinterpret_cast<const bf16x8*>(row);
                    bf16x8 v1 = *reinterpret_cast<const bf16x8*>(row + 8);
#pragma unroll
                    for (int q = 0; q < 8; ++q) {
                        a[q]     += bf2f((unsigned short)v0[q]);
                        a[8 + q] += bf2f((unsigned short)v1[q]);
                    }
                }
            }
        }
        float inv = (c > 0u) ? (1.0f / (float)c) : 0.0f;
#pragma unroll
        for (int q = 0; q < 16; ++q) a[q] *= inv;
        float4 A0 = {a[0], a[1], a[2], a[3]};
        float4 A1 = {a[4], a[5], a[6], a[7]};
        float4 A2 = {a[8], a[9], a[10], a[11]};
        float4 A3 = {a[12], a[13], a[14], a[15]};
        *reinterpret_cast<bf16x8*>(&X[nloc][p * 16])     = pack8(A0, A1);
        *reinterpret_cast<bf16x8*>(&X[nloc][p * 16 + 8]) = pack8(A2, A3);
    }
    __syncthreads();

    const int w    = tid >> 6;     // wave 0..7 -> j-slice [w*16, w*16+16)
    const int l    = tid & 63;
    const int lrow = l & 15;
    const int lkg  = l >> 4;

    f32x4 acc[4][4];   // [quadrant][mt]
#pragma unroll
    for (int q = 0; q < 4; q++)
#pragma unroll
        for (int mt = 0; mt < 4; mt++)
            acc[q][mt] = (f32x4){0.f, 0.f, 0.f, 0.f};

    for (int s = 0; s < 8; ++s) {
        bf16x8 A[4];
#pragma unroll
        for (int mt = 0; mt < 4; ++mt)
            A[mt] = *reinterpret_cast<const bf16x8*>(&X[mt * 16 + lrow][s * 32 + lkg * 8]);
#pragma unroll
        for (int q = 0; q < 4; ++q) {
            int t = q * 8 + w;
            bf16x8 B = *reinterpret_cast<const bf16x8*>(&wfrag[(size_t)(((t * 8 + s) * 64) + l) * 8]);
#pragma unroll
            for (int mt = 0; mt < 4; ++mt)
                acc[q][mt] = __builtin_amdgcn_mfma_f32_16x16x32_bf16(
                    A[mt], B, acc[q][mt], 0, 0, 0);
        }
    }

    const float ts0 = timestamps[0];

    {
        int j = w * 16 + lrow;
        float br  = b_ih[j]       + b_hh[j];
        float bz  = b_ih[128 + j] + b_hh[128 + j];
        float bin = b_ih[256 + j];
        float bhn = b_hh[256 + j];
#pragma unroll
        for (int mt = 0; mt < 4; ++mt) {
#pragma unroll
            for (int r = 0; r < 4; ++r) {
                int mloc = mt * 16 + lkg * 4 + r;
                int nodew = n0 + mloc;
                float rg  = acc[0][mt][r] + br;
                float zg  = acc[1][mt][r] + bz;
                float ing = acc[2][mt][r] + bin;
                float hng = acc[3][mt][r] + bhn;
                float rr = fsigmoid(rg);
                float zz = fsigmoid(zg);
                float nn = ftanh(ing + rr * hng);
                float mv = bf2f((unsigned short)X[mloc][128 + j]);
                float h  = (1.0f - zz) * nn + zz * mv;
                out[(size_t)nodew * 128 + j] = (cntS[mloc] > 0.0f) ? h : mv;
            }
        }
    }

    if (tid < GNT) {
        int noded = n0 + tid;
        out[(size_t)N_NODES * 128 + noded] = (cntS[tid] > 0.0f) ? ts0 : last_update[noded];
    }
}

// ---------------------------------------------------------------------------
// Fallback (round-7 proven): f32 atomics via d_out.
// ---------------------------------------------------------------------------
#define TE 32
#define GNTF 32

__global__ __launch_bounds__(256, 2) void tgn_msg_mfma(
    const float* __restrict__ memory,
    const float* __restrict__ last_update,
    const float* __restrict__ timestamps,
    const float* __restrict__ edge_features,
    const float* __restrict__ msg_b,
    const float* __restrict__ time_w,
    const float* __restrict__ time_b,
    const int*   __restrict__ src,
    const int*   __restrict__ dst,
    const short* __restrict__ wfm,
    float* __restrict__ sums,
    float* __restrict__ counts)
{
    __shared__ short X[TE][520];
    __shared__ int   sid[TE];
    __shared__ int   did[TE];
    __shared__ float dtS[TE];

    const int tid = threadIdx.x;
    const int e0  = blockIdx.x * TE;

    if (tid < TE) {
        int s = src[e0 + tid];
        int d = dst[e0 + tid];
        sid[tid] = s;
        did[tid] = d;
        dtS[tid] = timestamps[e0 + tid] - last_update[s];
        atomicAdd(&counts[s], 1.0f);
        atomicAdd(&counts[d], 1.0f);
    }
    __syncthreads();

    for (int i = tid; i < TE * 128; i += 256) {
        int e = i >> 7;
        int c = (i & 127) * 4;
        float4 v;
        if (c < 128) {
            v = *reinterpret_cast<const float4*>(&memory[(size_t)sid[e] * 128 + c]);
        } else if (c < 256) {
            v = *reinterpret_cast<const float4*>(&memory[(size_t)did[e] * 128 + (c - 128)]);
        } else if (c < 384) {
            v = *reinterpret_cast<const float4*>(&edge_features[(size_t)(e0 + e) * 128 + (c - 256)]);
        } else if (c < 484) {
            float dt = dtS[e];
            int t = c - 384;
            v.x = __cosf(fmaf(dt, time_w[t + 0], time_b[t + 0]));
            v.y = __cosf(fmaf(dt, time_w[t + 1], time_b[t + 1]));
            v.z = __cosf(fmaf(dt, time_w[t + 2], time_b[t + 2]));
            v.w = __cosf(fmaf(dt, time_w[t + 3], time_b[t + 3]));
        } else {
            v.x = v.y = v.z = v.w = 0.0f;
        }
        short4 s4;
        s4.x = f2bf(v.x); s4.y = f2bf(v.y); s4.z = f2bf(v.z); s4.w = f2bf(v.w);
        *reinterpret_cast<short4*>(&X[e][c]) = s4;
    }
    __syncthreads();

    const int w    = tid >> 6;
    const int l    = tid & 63;
    const int lrow = l & 15;
    const int lkg  = l >> 4;
    const int et   = w & 1;
    const int nh   = w >> 1;

    f32x4 acc[4];
#pragma unroll
    for (int n = 0; n < 4; n++) acc[n] = (f32x4){0.f, 0.f, 0.f, 0.f};

#pragma unroll 4
    for (int s = 0; s < 16; ++s) {
        bf16x8 A = *reinterpret_cast<const bf16x8*>(&X[et * 16 + lrow][s * 32 + lkg * 8]);
#pragma unroll
        for (int ntl = 0; ntl < 4; ++ntl) {
            int t = nh * 4 + ntl;
            bf16x8 B = *reinterpret_cast<const bf16x8*>(&wfm[(size_t)(((t * 16 + s) * 64) + l) * 8]);
            acc[ntl] = __builtin_amdgcn_mfma_f32_16x16x32_bf16(A, B, acc[ntl], 0, 0, 0);
        }
    }

#pragma unroll
    for (int ntl = 0; ntl < 4; ++ntl) {
        int j = nh * 64 + ntl * 16 + lrow;
        float bias = msg_b[j];
#pragma unroll
        for (int r = 0; r < 4; ++r) {
            int el = et * 16 + lkg * 4 + r;
            float m = acc[ntl][r] + bias;
            atomicAdd(&sums[(size_t)sid[el] * 128 + j], m);
            atomicAdd(&sums[(size_t)did[el] * 128 + j], m);
        }
    }
}

__global__ __launch_bounds__(256, 3) void tgn_gru_mfma(
    const float* __restrict__ memory,
    const float* __restrict__ last_update,
    const float* __restrict__ timestamps,
    const float* __restrict__ b_ih,
    const float* __restrict__ b_hh,
    const short* __restrict__ wfrag,
    float* __restrict__ out)
{
    __shared__ short X[GNTF][264];
    __shared__ float cntS[GNTF];

    const int tid = threadIdx.x;
    const int n0 = blockIdx.x * GNTF;
    const float* sums   = out;
    const float* counts = out + (size_t)N_NODES * 128;

    if (tid < GNTF) cntS[tid] = counts[n0 + tid];
    __syncthreads();

    for (int i = tid; i < GNTF * 32; i += 256) {
        int m = i >> 5;
        int c = (i & 31) * 4;
        float inv = 1.0f / fmaxf(cntS[m], 1.0f);
        float4 v = *reinterpret_cast<const float4*>(&sums[(size_t)(n0 + m) * 128 + c]);
        short4 a4;
        a4.x = f2bf(v.x * inv); a4.y = f2bf(v.y * inv);
        a4.z = f2bf(v.z * inv); a4.w = f2bf(v.w * inv);
        *reinterpret_cast<short4*>(&X[m][c]) = a4;
        float4 mv = *reinterpret_cast<const float4*>(&memory[(size_t)(n0 + m) * 128 + c]);
        short4 m4;
        m4.x = f2bf(mv.x); m4.y = f2bf(mv.y); m4.z = f2bf(mv.z); m4.w = f2bf(mv.w);
        *reinterpret_cast<short4*>(&X[m][128 + c]) = m4;
    }
    __syncthreads();

    const int w    = tid >> 6;
    const int l    = tid & 63;
    const int lrow = l & 15;
    const int lkg  = l >> 4;

    f32x4 acc[4][2][2];
#pragma unroll
    for (int q = 0; q < 4; q++)
#pragma unroll
        for (int jt = 0; jt < 2; jt++)
#pragma unroll
            for (int mt = 0; mt < 2; mt++)
                acc[q][jt][mt] = (f32x4){0.f, 0.f, 0.f, 0.f};

    for (int s = 0; s < 8; ++s) {
        bf16x8 A[2];
#pragma unroll
        for (int mt = 0; mt < 2; ++mt)
            A[mt] = *reinterpret_cast<const bf16x8*>(&X[mt * 16 + lrow][s * 32 + lkg * 8]);
#pragma unroll
        for (int q = 0; q < 4; ++q)
#pragma unroll
            for (int jt = 0; jt < 2; ++jt) {
                int t = q * 8 + w * 2 + jt;
                bf16x8 B = *reinterpret_cast<const bf16x8*>(&wfrag[(size_t)(((t * 8 + s) * 64) + l) * 8]);
#pragma unroll
                for (int mt = 0; mt < 2; ++mt)
                    acc[q][jt][mt] = __builtin_amdgcn_mfma_f32_16x16x32_bf16(
                        A[mt], B, acc[q][jt][mt], 0, 0, 0);
            }
    }

    const float ts0 = timestamps[0];
#pragma unroll
    for (int jt = 0; jt < 2; ++jt) {
        int j = w * 32 + jt * 16 + lrow;
        float br  = b_ih[j]       + b_hh[j];
        float bz  = b_ih[128 + j] + b_hh[128 + j];
        float bin = b_ih[256 + j];
        float bhn = b_hh[256 + j];
#pragma unroll
        for (int mt = 0; mt < 2; ++mt) {
#pragma unroll
            for (int r = 0; r < 4; ++r) {
                int mloc = mt * 16 + lkg * 4 + r;
                int node = n0 + mloc;
                float rg  = acc[0][jt][mt][r] + br;
                float zg  = acc[1][jt][mt][r] + bz;
                float ing = acc[2][jt][mt][r] + bin;
                float hng = acc[3][jt][mt][r] + bhn;
                float rr = fsigmoid(rg);
                float zz = fsigmoid(zg);
                float nn = ftanh(ing + rr * hng);
                float mv = memory[(size_t)node * 128 + j];
                float h  = (1.0f - zz) * nn + zz * mv;
                out[(size_t)node * 128 + j] = (cntS[mloc] > 0.0f) ? h : mv;
            }
        }
    }
    if (tid < GNTF) {
        int node = n0 + tid;
        out[(size_t)N_NODES * 128 + node] = (cntS[tid] > 0.0f) ? ts0 : last_update[node];
    }
}

// ---------------------------------------------------------------------------
extern "C" void kernel_launch(void* const* d_in, const int* in_sizes, int n_in,
                              void* d_out, int out_size, void* d_ws, size_t ws_size,
                              hipStream_t stream) {
    const float* memory        = (const float*)d_in[0];
    const float* last_update   = (const float*)d_in[1];
    const float* timestamps    = (const float*)d_in[2];
    const float* edge_features = (const float*)d_in[3];
    const float* msg_W         = (const float*)d_in[4];
    const float* msg_b         = (const float*)d_in[5];
    const float* gru_W_ih      = (const float*)d_in[6];
    const float* gru_W_hh      = (const float*)d_in[7];
    const float* gru_b_ih      = (const float*)d_in[8];
    const float* gru_b_hh      = (const float*)d_in[9];
    const float* time_w        = (const float*)d_in[10];
    const float* time_b        = (const float*)d_in[11];
    const int*   src           = (const int*)d_in[12];
    const int*   dst           = (const int*)d_in[13];

    float* out = (float*)d_out;
    char* ws = (char*)d_ws;

    const size_t OFF_WGRU = 0;                                   // 256 KB
    const size_t OFF_WMSG = 262144;                              // 128 KB
    const size_t OFF_MSG  = 393216;                              // E*128 bf16
    const size_t SZ_MSG   = (size_t)E_EDGES * 128 * 2;           // 25.6 MB
    const size_t OFF_IDX  = OFF_MSG + SZ_MSG;                    // N*CAP u32
    const size_t SZ_IDX   = (size_t)N_NODES * CAP * 4;           // 9.6 MB
    const size_t OFF_CNT  = OFF_IDX + SZ_IDX;                    // N u32
    const size_t OFF_OVF  = OFF_CNT + (size_t)N_NODES * 4;
    const size_t WS_NEED  = OFF_OVF + 4 + (size_t)OVF_MAX * 8;

    short* wfrag_gru = (short*)(ws + OFF_WGRU);
    short* wfrag_msg = (short*)(ws + OFF_WMSG);
    const int TICKET_BLOCKS = (E_EDGES + 255) / 256;             // 391

    if (ws_size >= WS_NEED) {
        short* msgb = (short*)(ws + OFF_MSG);
        uint*  idxv = (uint*)(ws + OFF_IDX);
        uint*  cnt  = (uint*)(ws + OFF_CNT);
        uint*  ovf  = (uint*)(ws + OFF_OVF);

        hipMemsetAsync(ws + OFF_CNT, 0, (size_t)N_NODES * 4 + 16, stream);

        tgn_setup<<<768 + TICKET_BLOCKS, 256, 0, stream>>>(
            gru_W_ih, gru_W_hh, wfrag_gru, msg_W, wfrag_msg,
            src, dst, idxv, cnt, ovf);

        tgn_msg_bf<<<E_EDGES / MTE, 128, 0, stream>>>(
            memory, last_update, timestamps, edge_features, msg_b,
            time_w, time_b, src, dst, wfrag_msg, msgb);

        tgn_gru_bf64<<<N_NODES / GNT, 512, 0, stream>>>(
            memory, last_update, timestamps, gru_b_ih, gru_b_hh, wfrag_gru,
            msgb, idxv, cnt, ovf, out);
    } else {
        hipMemsetAsync(d_out, 0, (size_t)out_size * sizeof(float), stream);
        float* sums   = out;
        float* counts = out + (size_t)N_NODES * 128;

        tgn_setup<<<768, 256, 0, stream>>>(
            gru_W_ih, gru_W_hh, wfrag_gru, msg_W, wfrag_msg,
            src, dst, nullptr, nullptr, nullptr);

        tgn_msg_mfma<<<E_EDGES / TE, 256, 0, stream>>>(
            memory, last_update, timestamps, edge_features, msg_b,
            time_w, time_b, src, dst, wfrag_msg, sums, counts);

        tgn_gru_mfma<<<N_NODES / GNTF, 256, 0, stream>>>(
            memory, last_update, timestamps, gru_b_ih, gru_b_hh, wfrag_gru, out);
    }
}